// Round 5
// baseline (259.491 us; speedup 1.0000x reference)
//
#include <hip/hip_runtime.h>

#define DEV __device__ __forceinline__

typedef __bf16 bf16;
typedef bf16 bf16x4 __attribute__((ext_vector_type(4)));
typedef bf16 bf16x8 __attribute__((ext_vector_type(8)));
typedef float f32x4 __attribute__((ext_vector_type(4)));

DEV f32x4 mfma16(bf16x8 a, bf16x8 b, f32x4 c) {
  return __builtin_amdgcn_mfma_f32_16x16x32_bf16(a, b, c, 0, 0, 0);
}

DEV void gload_lds16(const bf16* g, bf16* l) {
  __builtin_amdgcn_global_load_lds((const __attribute__((address_space(1))) void*)g,
                                   (__attribute__((address_space(3))) void*)l, 16, 0, 0);
}

#define WAITBAR(NSTR) asm volatile("s_waitcnt vmcnt(" NSTR ")\n\ts_barrier" ::: "memory")

// ---------------- LayerNorm (both param sets, shared mean/var) ----------------
__global__ __launch_bounds__(256) void ln_dual(
    const float* __restrict__ x,
    const float* __restrict__ w1, const float* __restrict__ b1,
    const float* __restrict__ w2, const float* __restrict__ b2,
    bf16* __restrict__ h1, bf16* __restrict__ h2)
{
  __shared__ float red[2][4];
  const int row = blockIdx.x, t = threadIdx.x;
  const int lane = t & 63, wave = t >> 6;
  const float4 v = ((const float4*)(x + (size_t)row * 1024))[t];
  float vv[4] = {v.x, v.y, v.z, v.w};
  float s = vv[0] + vv[1] + vv[2] + vv[3];
  float q = vv[0]*vv[0] + vv[1]*vv[1] + vv[2]*vv[2] + vv[3]*vv[3];
  #pragma unroll
  for (int o = 32; o; o >>= 1) { s += __shfl_xor(s, o); q += __shfl_xor(q, o); }
  if (lane == 0) { red[0][wave] = s; red[1][wave] = q; }
  __syncthreads();
  s = red[0][0] + red[0][1] + red[0][2] + red[0][3];
  q = red[1][0] + red[1][1] + red[1][2] + red[1][3];
  const float mu = s * (1.0f / 1024.0f);
  const float var = q * (1.0f / 1024.0f) - mu * mu;
  const float rs = rsqrtf(var + 1e-5f);
  bf16x4 o1, o2;
  #pragma unroll
  for (int j = 0; j < 4; ++j) {
    const int i = t * 4 + j;
    const float xh = (vv[j] - mu) * rs;
    o1[j] = (bf16)(xh * w1[i] + b1[i]);
    o2[j] = (bf16)(xh * w2[i] + b2[i]);
  }
  *(bf16x4*)&h1[(size_t)row * 1024 + t * 4] = o1;
  *(bf16x4*)&h2[(size_t)row * 1024 + t * 4] = o2;
}

// ---------------- f32 -> bf16 casts ----------------
__global__ __launch_bounds__(256) void cast_f32_bf16(
    const float* __restrict__ src, bf16* __restrict__ dst, int n4)
{
  const int i = blockIdx.x * 256 + threadIdx.x;
  if (i >= n4) return;
  const float4 v = ((const float4*)src)[i];
  bf16x4 o = {(bf16)v.x, (bf16)v.y, (bf16)v.z, (bf16)v.w};
  ((bf16x4*)dst)[i] = o;
}

__global__ __launch_bounds__(256) void cast_row(
    const float* __restrict__ src, bf16* __restrict__ dst, int ldd, int C)
{
  const int row = blockIdx.x;
  for (int off = threadIdx.x * 4; off < C; off += 1024) {
    const float4 v = *(const float4*)&src[(size_t)row * C + off];
    bf16x4 o = {(bf16)v.x, (bf16)v.y, (bf16)v.z, (bf16)v.w};
    *(bf16x4*)&dst[(size_t)row * ldd + off] = o;
  }
}

// ---------------- GEMM 256x256xBK64, 8 waves, 4-phase pipelined ----------------
DEV bf16x8 ldfrag(const bf16* unit, int lr, int g) {
  return *(const bf16x8*)&unit[lr * 32 + ((g ^ ((lr >> 1) & 3)) << 3)];
}
DEV void read_bfr(const bf16* unit, int blr, int g, bf16x8 bfr[4]) {
  #pragma unroll
  for (int nj = 0; nj < 4; ++nj) bfr[nj] = ldfrag(unit, blr + nj * 16, g);
}
DEV void read_af(const bf16* unit, int alr, int g, bf16x8 af[4]) {
  #pragma unroll
  for (int ml = 0; ml < 4; ++ml) af[ml] = ldfrag(unit, alr + ml * 16, g);
}
DEV void do_mfma(const bf16x8 af[4], const bf16x8 bfr[4], f32x4 acc[8][4], int mh) {
  __builtin_amdgcn_s_setprio(1);
  #pragma unroll
  for (int ml = 0; ml < 4; ++ml)
    #pragma unroll
    for (int nj = 0; nj < 4; ++nj)
      acc[mh * 4 + ml][nj] = mfma16(af[ml], bfr[nj], acc[mh * 4 + ml][nj]);
  __builtin_amdgcn_s_setprio(0);
}

// EPI: 0 = bf16 + bias; 1 = bf16 gelu(acc+bias); 2 = f32 partial (split-K, no bias;
//      sk==0 partial additionally adds xadd[idx])
template <int EPI>
__global__ __launch_bounds__(512, 2) void gemm256(
    const bf16* __restrict__ A, const bf16* __restrict__ B,
    const float* __restrict__ bias, void* __restrict__ Cv,
    float* __restrict__ P1, float* __restrict__ P2, float* __restrict__ P3,
    const float* __restrict__ xadd,
    int K, int ldc, int ntiles, int nbx, int nkt)
{
  __shared__ __align__(16) bf16 As[2][2][2][4096];
  __shared__ __align__(16) bf16 Bs[2][2][2][4096];
  const int tid = threadIdx.x;
  const int lane = tid & 63, wave = tid >> 6;
  const int wm = wave >> 2, wn = wave & 3;
  const int g = lane >> 4, c = lane & 15;
  const int cpx = gridDim.x >> 3;
  const int swz = ((int)blockIdx.x & 7) * cpx + ((int)blockIdx.x >> 3);
  const int tile = swz % ntiles;
  const int sk = swz / ntiles;
  const int bm = (tile / nbx) * 256, bn = (tile % nbx) * 256;

  const int slr = tid >> 2;
  const int sch = (tid & 3) ^ ((tid >> 3) & 3);
  const bf16* aU[2][2];
  const bf16* bU[2][2];
  {
    const bf16* a0 = A + (size_t)(bm + ((slr >> 6) * 128) + (slr & 63)) * K
                       + (size_t)sk * nkt * 64 + sch * 8;
    const bf16* b0 = B + (size_t)(bn + slr) * K + (size_t)sk * nkt * 64 + sch * 8;
    aU[0][0] = a0;            aU[0][1] = a0 + (size_t)64 * K;
    aU[1][0] = a0 + 32;       aU[1][1] = a0 + (size_t)64 * K + 32;
    bU[0][0] = b0;            bU[0][1] = b0 + (size_t)128 * K;
    bU[1][0] = b0 + 32;       bU[1][1] = b0 + (size_t)128 * K + 32;
  }
#define STG_A(bf_, kkh_, ub_, ko_) gload_lds16(aU[kkh_][ub_] + (ko_), &As[bf_][kkh_][ub_][wave * 512])
#define STG_B(bf_, kkh_, ub_, ko_) gload_lds16(bU[kkh_][ub_] + (ko_), &Bs[bf_][kkh_][ub_][wave * 512])

  f32x4 acc[8][4] = {};
  bf16x8 bfr[4], af[4];
  const int alr = (wm << 6) + c;
  const int blr = ((wn & 1) << 6) + c;
  const int bub = wn >> 1;

  STG_B(0, 0, 0, 0); STG_B(0, 0, 1, 0); STG_A(0, 0, 0, 0); STG_A(0, 0, 1, 0);
  STG_B(0, 1, 0, 0); STG_B(0, 1, 1, 0); STG_A(0, 1, 0, 0); STG_A(0, 1, 1, 0);

  for (int t = 0; t < nkt - 1; ++t) {
    const int buf = t & 1, nxt = buf ^ 1;
    const int ko = (t + 1) * 64;
    STG_B(nxt, 0, 0, ko); STG_B(nxt, 0, 1, ko);
    WAITBAR("6");
    read_bfr(&Bs[buf][0][bub][0], blr, g, bfr);
    read_af(&As[buf][0][0][0], alr, g, af);
    do_mfma(af, bfr, acc, 0);
    STG_A(nxt, 0, 0, ko); STG_A(nxt, 0, 1, ko);
    WAITBAR("6");
    read_af(&As[buf][0][1][0], alr, g, af);
    do_mfma(af, bfr, acc, 1);
    STG_B(nxt, 1, 0, ko); STG_B(nxt, 1, 1, ko);
    WAITBAR("6");
    read_bfr(&Bs[buf][1][bub][0], blr, g, bfr);
    read_af(&As[buf][1][0][0], alr, g, af);
    do_mfma(af, bfr, acc, 0);
    STG_A(nxt, 1, 0, ko); STG_A(nxt, 1, 1, ko);
    WAITBAR("6");
    read_af(&As[buf][1][1][0], alr, g, af);
    do_mfma(af, bfr, acc, 1);
  }
  {
    const int buf = (nkt - 1) & 1;
    WAITBAR("4");
    read_bfr(&Bs[buf][0][bub][0], blr, g, bfr);
    read_af(&As[buf][0][0][0], alr, g, af);
    do_mfma(af, bfr, acc, 0);
    read_af(&As[buf][0][1][0], alr, g, af);
    do_mfma(af, bfr, acc, 1);
    WAITBAR("1");
    read_bfr(&Bs[buf][1][bub][0], blr, g, bfr);
    read_af(&As[buf][1][0][0], alr, g, af);
    do_mfma(af, bfr, acc, 0);
    WAITBAR("0");
    read_af(&As[buf][1][1][0], alr, g, af);
    do_mfma(af, bfr, acc, 1);
  }
#undef STG_A
#undef STG_B

  float* Pp = nullptr;
  if constexpr (EPI == 2) Pp = (sk == 1) ? P1 : (sk == 2) ? P2 : (sk == 3) ? P3 : (float*)Cv;
  const int row0 = bm + wm * 128 + 4 * g;
  const int col0 = bn + wn * 64 + c;
  #pragma unroll
  for (int mi = 0; mi < 8; ++mi) {
    #pragma unroll
    for (int nj = 0; nj < 4; ++nj) {
      const int col = col0 + nj * 16;
      float bv = 0.0f;
      if constexpr (EPI < 2) bv = bias[col];
      #pragma unroll
      for (int r = 0; r < 4; ++r) {
        const size_t idx = (size_t)(row0 + mi * 16 + r) * ldc + col;
        float vo = acc[mi][nj][r] + bv;
        if constexpr (EPI == 0) {
          ((bf16*)Cv)[idx] = (bf16)vo;
        } else if constexpr (EPI == 1) {
          ((bf16*)Cv)[idx] = (bf16)(0.5f * vo * (1.0f + erff(vo * 0.70710678118f)));
        } else {
          if (sk == 0) vo += xadd[idx];
          Pp[idx] = vo;
        }
      }
    }
  }
}

// ---------------- combine: out = p3(=out) + p0 + p1 + p2 + b_o + b2 ----------------
__global__ __launch_bounds__(256) void combine_out(
    const float* __restrict__ p0, const float* __restrict__ p1,
    const float* __restrict__ p2,
    const float* __restrict__ bo, const float* __restrict__ b2,
    float* __restrict__ out)
{
  const int row = blockIdx.x, t = threadIdx.x;
  const size_t base = (size_t)row * 1024 + t * 4;
  float4 a = *(float4*)&out[base];
  const float4 v0 = *(const float4*)&p0[base];
  const float4 v1 = *(const float4*)&p1[base];
  const float4 v2 = *(const float4*)&p2[base];
  const float4 vb = *(const float4*)&bo[t * 4];
  const float4 vc = *(const float4*)&b2[t * 4];
  a.x += v0.x + v1.x + v2.x + vb.x + vc.x;
  a.y += v0.y + v1.y + v2.y + vb.y + vc.y;
  a.z += v0.z + v1.z + v2.z + vb.z + vc.z;
  a.w += v0.w + v1.w + v2.w + vb.w + vc.w;
  *(float4*)&out[base] = a;
}

// ---------------- RoPE + head reshape; also writes V^T ----------------
__global__ __launch_bounds__(256) void rope_reshape(
    const bf16* __restrict__ qkv, const float* __restrict__ freqs,
    bf16* __restrict__ Q, bf16* __restrict__ K, bf16* __restrict__ VT)
{
  __shared__ bf16 vt[64][72];
  const int t = threadIdx.x;
  const int bh = blockIdx.y, b = bh >> 4, h = bh & 15;
  const int sc = blockIdx.x * 64;
  const int sl = t >> 2, s = sc + sl;
  const int d0 = (t & 3) * 16;

  const size_t rowbase = (size_t)(b * 2048 + s) * 3072 + h * 64 + d0;
  const size_t obase = ((size_t)bh * 2048 + s) * 64 + d0;

  #pragma unroll
  for (int which = 0; which < 2; ++which) {
    const bf16* src = qkv + rowbase + which * 1024;
    bf16x8 v0 = *(const bf16x8*)src;
    bf16x8 v1 = *(const bf16x8*)(src + 8);
    if (d0 == 0) {
      bf16x8 r0, r1;
      #pragma unroll
      for (int j = 0; j < 8; ++j) {
        const float cs = freqs[s * 16 + j * 2];
        const float sn = freqs[s * 16 + j * 2 + 1];
        const float x1 = (float)v0[j], x2 = (float)v1[j];
        r0[j] = (bf16)(x1 * cs - x2 * sn);
        r1[j] = (bf16)(x1 * sn + x2 * cs);
      }
      v0 = r0; v1 = r1;
    }
    bf16* dst = (which == 0 ? Q : K) + obase;
    *(bf16x8*)dst = v0;
    *(bf16x8*)(dst + 8) = v1;
  }
  {
    const bf16* src = qkv + rowbase + 2048;
    bf16x8 v0 = *(const bf16x8*)src;
    bf16x8 v1 = *(const bf16x8*)(src + 8);
    #pragma unroll
    for (int j = 0; j < 8; ++j) { vt[sl][d0 + j] = v0[j]; vt[sl][d0 + 8 + j] = v1[j]; }
  }
  __syncthreads();
  {
    const int d = t >> 2;
    const int s0 = (t & 3) * 16;
    bf16x8 o0, o1;
    #pragma unroll
    for (int j = 0; j < 8; ++j) { o0[j] = vt[s0 + j][d]; o1[j] = vt[s0 + 8 + j][d]; }
    bf16* dst = VT + ((size_t)bh * 64 + d) * 2048 + sc + s0;
    *(bf16x8*)dst = o0;
    *(bf16x8*)(dst + 8) = o1;
  }
}

// ---------------- Causal flash attention (v3) ----------------
// Grid: 512 blocks 1-D with complementary pairing: L<256 -> (bh=L/16, qt=L%16);
// L>=256 -> (bh=16+(L-256)/16, qt=15-((L-256)%16)). Blocks L and L+256 co-reside
// on a CU -> per-CU work uniform (34 tile-units).
// Scores in log2 domain (0.125*log2e folded into Q regs) -> softmax uses raw
// v_exp_f32. Defer-max (T13, THR=8 log2): skip O-rescale while max growth <= 8.
__global__ __launch_bounds__(512, 4) void attn_kernel(
    const bf16* __restrict__ Q, const bf16* __restrict__ Kg,
    const bf16* __restrict__ VTg, bf16* __restrict__ O, int ldO)
{
  __shared__ __align__(16) bf16 Ks[2][64][64];
  __shared__ __align__(16) bf16 Vs[2][64][64];
  __shared__ __align__(16) bf16 Ps[8][16][64];

  const int tid = threadIdx.x;
  const int lane = tid & 63, wave = tid >> 6;
  const int g = lane >> 4, c = lane & 15;
  const int L = blockIdx.x;
  const int half = L >> 8, r = L & 255;
  const int bh = (half << 4) | (r >> 4);
  const int qtile = half ? (15 - (r & 15)) : (r & 15);
  const int qw = qtile * 128 + wave * 16;

  const bf16* Qp = Q + (size_t)bh * 2048 * 64;
  const bf16* Kp = Kg + (size_t)bh * 2048 * 64;
  const bf16* Vp = VTg + (size_t)bh * 64 * 2048;

  const int srow = lane >> 3;
  const int schunk = (lane & 7) ^ srow;
  const int svr = wave * 8 + srow;
  bf16* kdst = &Ks[0][wave * 8][0];
  bf16* vdst = &Vs[0][wave * 8][0];
  const size_t kdelta = (size_t)64 * 64;

  // Q fragments, scaled into log2 domain: S_log2 = (QK^T)*0.125*log2(e)
  bf16x8 qreg[2];
  {
    const float qs = 0.125f * 1.44269504f;
    bf16x8 t0 = *(const bf16x8*)&Qp[(size_t)(qw + c) * 64 + g * 8];
    bf16x8 t1 = *(const bf16x8*)&Qp[(size_t)(qw + c) * 64 + 32 + g * 8];
    #pragma unroll
    for (int j = 0; j < 8; ++j) {
      qreg[0][j] = (bf16)((float)t0[j] * qs);
      qreg[1][j] = (bf16)((float)t1[j] * qs);
    }
  }

  // hoisted LDS offsets
  const int cq = c & 7;
  int fo[4][2];
  #pragma unroll
  for (int i = 0; i < 4; ++i)
    #pragma unroll
    for (int kk = 0; kk < 2; ++kk)
      fo[i][kk] = (i * 16 + c) * 64 + (((kk * 4 + g) ^ cq) << 3);
  bf16* pw[4];
  #pragma unroll
  for (int kf = 0; kf < 4; ++kf)
    pw[kf] = &Ps[wave][c][((((kf * 2 + (g >> 1)) ^ cq) << 3)) + ((g & 1) << 2)];
  const bf16* pr[2];
  #pragma unroll
  for (int kk = 0; kk < 2; ++kk)
    pr[kk] = &Ps[wave][c][((kk * 4 + g) ^ cq) << 3];
  const bf16* ks0 = &Ks[0][0][0];
  const bf16* vs0 = &Vs[0][0][0];

  f32x4 oacc[4] = {};
  float m_ = -1e30f, l_ = 0.0f;

  const int nkb = 2 * qtile + 2;
  gload_lds16(&Kp[(size_t)(svr) * 64 + schunk * 8], kdst);
  gload_lds16(&Vp[(size_t)(svr) * 2048 + schunk * 8], vdst);
  asm volatile("s_waitcnt vmcnt(0)" ::: "memory");
  __builtin_amdgcn_s_barrier();

  for (int kb = 0; kb < nkb; ++kb) {
    const int cur = kb & 1;
    const int kbase = kb * 64;
    if (kb + 1 < nkb) {
      const int nb = kbase + 64;
      gload_lds16(&Kp[(size_t)(nb + svr) * 64 + schunk * 8], kdst + (cur ^ 1) * kdelta);
      gload_lds16(&Vp[(size_t)(svr) * 2048 + nb + schunk * 8], vdst + (cur ^ 1) * kdelta);
    }
    if (kbase <= qw + 15) {
      const bf16* kt = ks0 + cur * kdelta;
      f32x4 st[4] = {};
      #pragma unroll
      for (int kf = 0; kf < 4; ++kf)
        #pragma unroll
        for (int kk = 0; kk < 2; ++kk)
          st[kf] = mfma16(*(const bf16x8*)(kt + fo[kf][kk]), qreg[kk], st[kf]);

      // masked scores (log2 domain)
      float v[16];
      if (kbase + 63 > qw) {
        const int qrel = qw + c - kbase;
        #pragma unroll
        for (int kf = 0; kf < 4; ++kf)
          #pragma unroll
          for (int rr = 0; rr < 4; ++rr)
            v[kf * 4 + rr] = (kf * 16 + 4 * g + rr <= qrel) ? st[kf][rr] : -1e30f;
      } else {
        #pragma unroll
        for (int kf = 0; kf < 4; ++kf)
          #pragma unroll
          for (int rr = 0; rr < 4; ++rr)
            v[kf * 4 + rr] = st[kf][rr];
      }
      // max tree (depth 4) + cross-g reduce
      float a0 = fmaxf(v[0], v[1]),  a1 = fmaxf(v[2], v[3]);
      float a2 = fmaxf(v[4], v[5]),  a3 = fmaxf(v[6], v[7]);
      float a4 = fmaxf(v[8], v[9]),  a5 = fmaxf(v[10], v[11]);
      float a6 = fmaxf(v[12], v[13]), a7 = fmaxf(v[14], v[15]);
      float b0 = fmaxf(a0, a1), b1 = fmaxf(a2, a3), b2_ = fmaxf(a4, a5), b3 = fmaxf(a6, a7);
      float tm = fmaxf(fmaxf(b0, b1), fmaxf(b2_, b3));
      tm = fmaxf(tm, __shfl_xor(tm, 16));
      tm = fmaxf(tm, __shfl_xor(tm, 32));
      // defer-max: only rescale when max grew by > 8 (=> P <= 2^8, bf16-safe)
      if (__any(tm > m_ + 8.0f)) {
        const float mn = fmaxf(m_, tm);
        const float alpha = __builtin_amdgcn_exp2f(m_ - mn);
        m_ = mn;
        l_ *= alpha;
        #pragma unroll
        for (int df = 0; df < 4; ++df) {
          oacc[df][0] *= alpha; oacc[df][1] *= alpha;
          oacc[df][2] *= alpha; oacc[df][3] *= alpha;
        }
      }
      float ts = 0.0f;
      bf16 p[16];
      #pragma unroll
      for (int i = 0; i < 16; ++i) {
        const float pv = __builtin_amdgcn_exp2f(v[i] - m_);
        ts += pv;
        p[i] = (bf16)pv;
      }
      ts += __shfl_xor(ts, 16);
      ts += __shfl_xor(ts, 32);
      l_ += ts;
      #pragma unroll
      for (int kf = 0; kf < 4; ++kf) {
        bf16x4 pk = {p[kf * 4], p[kf * 4 + 1], p[kf * 4 + 2], p[kf * 4 + 3]};
        *(bf16x4*)pw[kf] = pk;
      }
      bf16x8 pfrag[2];
      pfrag[0] = *(const bf16x8*)pr[0];
      pfrag[1] = *(const bf16x8*)pr[1];
      const bf16* vt = vs0 + cur * kdelta;
      #pragma unroll
      for (int df = 0; df < 4; ++df)
        #pragma unroll
        for (int kk = 0; kk < 2; ++kk)
          oacc[df] = mfma16(*(const bf16x8*)(vt + fo[df][kk]), pfrag[kk], oacc[df]);
    }
    asm volatile("s_waitcnt vmcnt(0)" ::: "memory");
    __builtin_amdgcn_s_barrier();
  }

  const int b = bh >> 4, h = bh & 15;
  const float inv = 1.0f / l_;
  const int s = qw + c;
  #pragma unroll
  for (int df = 0; df < 4; ++df) {
    bf16x4 o;
    #pragma unroll
    for (int rr = 0; rr < 4; ++rr) o[rr] = (bf16)(oacc[df][rr] * inv);
    *(bf16x4*)&O[(size_t)(b * 2048 + s) * ldO + h * 64 + df * 16 + 4 * g] = o;
  }
}

// ---------------- host orchestration ----------------
extern "C" void kernel_launch(void* const* d_in, const int* in_sizes, int n_in,
                              void* d_out, int out_size, void* d_ws, size_t ws_size,
                              hipStream_t stream) {
  const float* x     = (const float*)d_in[0];
  const float* W_qkv = (const float*)d_in[2];
  const float* b_qkv = (const float*)d_in[3];
  const float* W_o   = (const float*)d_in[4];
  const float* b_o   = (const float*)d_in[5];
  const float* ln1w  = (const float*)d_in[6];
  const float* ln1b  = (const float*)d_in[7];
  const float* ln2w  = (const float*)d_in[8];
  const float* ln2b  = (const float*)d_in[9];
  const float* W1    = (const float*)d_in[10];
  const float* b1    = (const float*)d_in[11];
  const float* W2    = (const float*)d_in[12];
  const float* b2    = (const float*)d_in[13];
  const float* freqs = (const float*)d_in[14];
  float* out = (float*)d_out;

  char* ws = (char*)d_ws;
  const size_t MB = (size_t)1 << 20;
  bf16* h1   = (bf16*)(ws + 0 * MB);
  bf16* h2   = (bf16*)(ws + 8 * MB);
  bf16* wQKV = (bf16*)(ws + 16 * MB);
  bf16* wCat = (bf16*)(ws + 22 * MB);
  bf16* w1   = (bf16*)(ws + 32 * MB);
  bf16* qkv  = (bf16*)(ws + 40 * MB);
  bf16* Qb   = (bf16*)(ws + 64 * MB);
  bf16* Kb   = (bf16*)(ws + 72 * MB);
  bf16* VTb  = (bf16*)(ws + 80 * MB);
  bf16* A2   = (bf16*)(ws + 88 * MB);
  float* p0  = (float*)(ws + 0 * MB);
  float* p1  = (float*)(ws + 40 * MB);
  float* p2  = (float*)(ws + 64 * MB);

  ln_dual<<<4096, 256, 0, stream>>>(x, ln1w, ln1b, ln2w, ln2b, h1, h2);
  cast_f32_bf16<<<3072, 256, 0, stream>>>(W_qkv, wQKV, 786432);
  cast_f32_bf16<<<4096, 256, 0, stream>>>(W1, w1, 1048576);
  cast_row<<<1024, 256, 0, stream>>>(W_o, wCat, 5120, 1024);
  cast_row<<<1024, 256, 0, stream>>>(W2, wCat + 1024, 5120, 4096);

  gemm256<0><<<192, 512, 0, stream>>>(h1, wQKV, b_qkv, qkv,
                                      nullptr, nullptr, nullptr, nullptr,
                                      1024, 3072, 192, 12, 16);
  rope_reshape<<<dim3(32, 32), 256, 0, stream>>>(qkv, freqs, Qb, Kb, VTb);
  attn_kernel<<<512, 512, 0, stream>>>(Qb, Kb, VTb, A2, 5120);
  gemm256<1><<<256, 512, 0, stream>>>(h2, w1, b1, A2 + 1024,
                                      nullptr, nullptr, nullptr, nullptr,
                                      1024, 5120, 256, 16, 16);
  gemm256<2><<<256, 512, 0, stream>>>(A2, wCat, nullptr, p0,
                                      p1, p2, out, x,
                                      5120, 1024, 64, 4, 20);
  combine_out<<<4096, 256, 0, stream>>>(p0, p1, p2, b_o, b2, out);
}

// Round 6
// 259.108 us; speedup vs baseline: 1.0015x; 1.0015x over previous
//
#include <hip/hip_runtime.h>

#define DEV __device__ __forceinline__

typedef __bf16 bf16;
typedef bf16 bf16x4 __attribute__((ext_vector_type(4)));
typedef bf16 bf16x8 __attribute__((ext_vector_type(8)));
typedef float f32x4 __attribute__((ext_vector_type(4)));

DEV f32x4 mfma16(bf16x8 a, bf16x8 b, f32x4 c) {
  return __builtin_amdgcn_mfma_f32_16x16x32_bf16(a, b, c, 0, 0, 0);
}

DEV void gload_lds16(const bf16* g, bf16* l) {
  __builtin_amdgcn_global_load_lds((const __attribute__((address_space(1))) void*)g,
                                   (__attribute__((address_space(3))) void*)l, 16, 0, 0);
}

#define WAITBAR(NSTR) asm volatile("s_waitcnt vmcnt(" NSTR ")\n\ts_barrier" ::: "memory")

// ---------------- LayerNorm (both param sets, shared mean/var) ----------------
__global__ __launch_bounds__(256) void ln_dual(
    const float* __restrict__ x,
    const float* __restrict__ w1, const float* __restrict__ b1,
    const float* __restrict__ w2, const float* __restrict__ b2,
    bf16* __restrict__ h1, bf16* __restrict__ h2)
{
  __shared__ float red[2][4];
  const int row = blockIdx.x, t = threadIdx.x;
  const int lane = t & 63, wave = t >> 6;
  const float4 v = ((const float4*)(x + (size_t)row * 1024))[t];
  float vv[4] = {v.x, v.y, v.z, v.w};
  float s = vv[0] + vv[1] + vv[2] + vv[3];
  float q = vv[0]*vv[0] + vv[1]*vv[1] + vv[2]*vv[2] + vv[3]*vv[3];
  #pragma unroll
  for (int o = 32; o; o >>= 1) { s += __shfl_xor(s, o); q += __shfl_xor(q, o); }
  if (lane == 0) { red[0][wave] = s; red[1][wave] = q; }
  __syncthreads();
  s = red[0][0] + red[0][1] + red[0][2] + red[0][3];
  q = red[1][0] + red[1][1] + red[1][2] + red[1][3];
  const float mu = s * (1.0f / 1024.0f);
  const float var = q * (1.0f / 1024.0f) - mu * mu;
  const float rs = rsqrtf(var + 1e-5f);
  bf16x4 o1, o2;
  #pragma unroll
  for (int j = 0; j < 4; ++j) {
    const int i = t * 4 + j;
    const float xh = (vv[j] - mu) * rs;
    o1[j] = (bf16)(xh * w1[i] + b1[i]);
    o2[j] = (bf16)(xh * w2[i] + b2[i]);
  }
  *(bf16x4*)&h1[(size_t)row * 1024 + t * 4] = o1;
  *(bf16x4*)&h2[(size_t)row * 1024 + t * 4] = o2;
}

// ---------------- f32 -> bf16 casts ----------------
__global__ __launch_bounds__(256) void cast_f32_bf16(
    const float* __restrict__ src, bf16* __restrict__ dst, int n4)
{
  const int i = blockIdx.x * 256 + threadIdx.x;
  if (i >= n4) return;
  const float4 v = ((const float4*)src)[i];
  bf16x4 o = {(bf16)v.x, (bf16)v.y, (bf16)v.z, (bf16)v.w};
  ((bf16x4*)dst)[i] = o;
}

__global__ __launch_bounds__(256) void cast_row(
    const float* __restrict__ src, bf16* __restrict__ dst, int ldd, int C)
{
  const int row = blockIdx.x;
  for (int off = threadIdx.x * 4; off < C; off += 1024) {
    const float4 v = *(const float4*)&src[(size_t)row * C + off];
    bf16x4 o = {(bf16)v.x, (bf16)v.y, (bf16)v.z, (bf16)v.w};
    *(bf16x4*)&dst[(size_t)row * ldd + off] = o;
  }
}

// ---------------- GEMM 256x256xBK64, 8 waves, 4-phase pipelined ----------------
DEV bf16x8 ldfrag(const bf16* unit, int lr, int g) {
  return *(const bf16x8*)&unit[lr * 32 + ((g ^ ((lr >> 1) & 3)) << 3)];
}
DEV void read_bfr(const bf16* unit, int blr, int g, bf16x8 bfr[4]) {
  #pragma unroll
  for (int nj = 0; nj < 4; ++nj) bfr[nj] = ldfrag(unit, blr + nj * 16, g);
}
DEV void read_af(const bf16* unit, int alr, int g, bf16x8 af[4]) {
  #pragma unroll
  for (int ml = 0; ml < 4; ++ml) af[ml] = ldfrag(unit, alr + ml * 16, g);
}
DEV void do_mfma(const bf16x8 af[4], const bf16x8 bfr[4], f32x4 acc[8][4], int mh) {
  __builtin_amdgcn_s_setprio(1);
  #pragma unroll
  for (int ml = 0; ml < 4; ++ml)
    #pragma unroll
    for (int nj = 0; nj < 4; ++nj)
      acc[mh * 4 + ml][nj] = mfma16(af[ml], bfr[nj], acc[mh * 4 + ml][nj]);
  __builtin_amdgcn_s_setprio(0);
}

// EPI: 0 = bf16 + bias; 1 = bf16 gelu(acc+bias); 2 = f32 partial (split-K, no bias;
//      sk==0 partial additionally adds xadd[idx])
// NOTE: __launch_bounds__(512) with NO min-waves arg — acc[8][4] alone is 128
// VGPRs; a (512,2) bound caps allocation at 128 and spills the accumulator to
// scratch (R5: VGPR_Count==128, MfmaUtil 20%, 15x slowdown). 512-thread blocks
// already force <=256 VGPR, which still gives 2 waves/SIMD (m69).
template <int EPI>
__global__ __launch_bounds__(512) void gemm256(
    const bf16* __restrict__ A, const bf16* __restrict__ B,
    const float* __restrict__ bias, void* __restrict__ Cv,
    float* __restrict__ P1, float* __restrict__ P2, float* __restrict__ P3,
    const float* __restrict__ xadd,
    int K, int ldc, int ntiles, int nbx, int nkt)
{
  __shared__ __align__(16) bf16 As[2][2][2][4096];
  __shared__ __align__(16) bf16 Bs[2][2][2][4096];
  const int tid = threadIdx.x;
  const int lane = tid & 63, wave = tid >> 6;
  const int wm = wave >> 2, wn = wave & 3;
  const int g = lane >> 4, c = lane & 15;
  const int cpx = gridDim.x >> 3;
  const int swz = ((int)blockIdx.x & 7) * cpx + ((int)blockIdx.x >> 3);
  const int tile = swz % ntiles;
  const int sk = swz / ntiles;
  const int bm = (tile / nbx) * 256, bn = (tile % nbx) * 256;

  const int slr = tid >> 2;
  const int sch = (tid & 3) ^ ((tid >> 3) & 3);
  const bf16* aU[2][2];
  const bf16* bU[2][2];
  {
    const bf16* a0 = A + (size_t)(bm + ((slr >> 6) * 128) + (slr & 63)) * K
                       + (size_t)sk * nkt * 64 + sch * 8;
    const bf16* b0 = B + (size_t)(bn + slr) * K + (size_t)sk * nkt * 64 + sch * 8;
    aU[0][0] = a0;            aU[0][1] = a0 + (size_t)64 * K;
    aU[1][0] = a0 + 32;       aU[1][1] = a0 + (size_t)64 * K + 32;
    bU[0][0] = b0;            bU[0][1] = b0 + (size_t)128 * K;
    bU[1][0] = b0 + 32;       bU[1][1] = b0 + (size_t)128 * K + 32;
  }
#define STG_A(bf_, kkh_, ub_, ko_) gload_lds16(aU[kkh_][ub_] + (ko_), &As[bf_][kkh_][ub_][wave * 512])
#define STG_B(bf_, kkh_, ub_, ko_) gload_lds16(bU[kkh_][ub_] + (ko_), &Bs[bf_][kkh_][ub_][wave * 512])

  f32x4 acc[8][4] = {};
  bf16x8 bfr[4], af[4];
  const int alr = (wm << 6) + c;
  const int blr = ((wn & 1) << 6) + c;
  const int bub = wn >> 1;

  STG_B(0, 0, 0, 0); STG_B(0, 0, 1, 0); STG_A(0, 0, 0, 0); STG_A(0, 0, 1, 0);
  STG_B(0, 1, 0, 0); STG_B(0, 1, 1, 0); STG_A(0, 1, 0, 0); STG_A(0, 1, 1, 0);

  for (int t = 0; t < nkt - 1; ++t) {
    const int buf = t & 1, nxt = buf ^ 1;
    const int ko = (t + 1) * 64;
    STG_B(nxt, 0, 0, ko); STG_B(nxt, 0, 1, ko);
    WAITBAR("6");
    read_bfr(&Bs[buf][0][bub][0], blr, g, bfr);
    read_af(&As[buf][0][0][0], alr, g, af);
    do_mfma(af, bfr, acc, 0);
    STG_A(nxt, 0, 0, ko); STG_A(nxt, 0, 1, ko);
    WAITBAR("6");
    read_af(&As[buf][0][1][0], alr, g, af);
    do_mfma(af, bfr, acc, 1);
    STG_B(nxt, 1, 0, ko); STG_B(nxt, 1, 1, ko);
    WAITBAR("6");
    read_bfr(&Bs[buf][1][bub][0], blr, g, bfr);
    read_af(&As[buf][1][0][0], alr, g, af);
    do_mfma(af, bfr, acc, 0);
    STG_A(nxt, 1, 0, ko); STG_A(nxt, 1, 1, ko);
    WAITBAR("6");
    read_af(&As[buf][1][1][0], alr, g, af);
    do_mfma(af, bfr, acc, 1);
  }
  {
    const int buf = (nkt - 1) & 1;
    WAITBAR("4");
    read_bfr(&Bs[buf][0][bub][0], blr, g, bfr);
    read_af(&As[buf][0][0][0], alr, g, af);
    do_mfma(af, bfr, acc, 0);
    read_af(&As[buf][0][1][0], alr, g, af);
    do_mfma(af, bfr, acc, 1);
    WAITBAR("1");
    read_bfr(&Bs[buf][1][bub][0], blr, g, bfr);
    read_af(&As[buf][1][0][0], alr, g, af);
    do_mfma(af, bfr, acc, 0);
    WAITBAR("0");
    read_af(&As[buf][1][1][0], alr, g, af);
    do_mfma(af, bfr, acc, 1);
  }
#undef STG_A
#undef STG_B

  float* Pp = nullptr;
  if constexpr (EPI == 2) Pp = (sk == 1) ? P1 : (sk == 2) ? P2 : (sk == 3) ? P3 : (float*)Cv;
  const int row0 = bm + wm * 128 + 4 * g;
  const int col0 = bn + wn * 64 + c;
  #pragma unroll
  for (int mi = 0; mi < 8; ++mi) {
    #pragma unroll
    for (int nj = 0; nj < 4; ++nj) {
      const int col = col0 + nj * 16;
      float bv = 0.0f;
      if constexpr (EPI < 2) bv = bias[col];
      #pragma unroll
      for (int r = 0; r < 4; ++r) {
        const size_t idx = (size_t)(row0 + mi * 16 + r) * ldc + col;
        float vo = acc[mi][nj][r] + bv;
        if constexpr (EPI == 0) {
          ((bf16*)Cv)[idx] = (bf16)vo;
        } else if constexpr (EPI == 1) {
          ((bf16*)Cv)[idx] = (bf16)(0.5f * vo * (1.0f + erff(vo * 0.70710678118f)));
        } else {
          if (sk == 0) vo += xadd[idx];
          Pp[idx] = vo;
        }
      }
    }
  }
}

// ---------------- combine: out = p3(=out) + p0 + p1 + p2 + b_o + b2 ----------------
__global__ __launch_bounds__(256) void combine_out(
    const float* __restrict__ p0, const float* __restrict__ p1,
    const float* __restrict__ p2,
    const float* __restrict__ bo, const float* __restrict__ b2,
    float* __restrict__ out)
{
  const int row = blockIdx.x, t = threadIdx.x;
  const size_t base = (size_t)row * 1024 + t * 4;
  float4 a = *(float4*)&out[base];
  const float4 v0 = *(const float4*)&p0[base];
  const float4 v1 = *(const float4*)&p1[base];
  const float4 v2 = *(const float4*)&p2[base];
  const float4 vb = *(const float4*)&bo[t * 4];
  const float4 vc = *(const float4*)&b2[t * 4];
  a.x += v0.x + v1.x + v2.x + vb.x + vc.x;
  a.y += v0.y + v1.y + v2.y + vb.y + vc.y;
  a.z += v0.z + v1.z + v2.z + vb.z + vc.z;
  a.w += v0.w + v1.w + v2.w + vb.w + vc.w;
  *(float4*)&out[base] = a;
}

// ---------------- RoPE + head reshape; also writes V^T ----------------
__global__ __launch_bounds__(256) void rope_reshape(
    const bf16* __restrict__ qkv, const float* __restrict__ freqs,
    bf16* __restrict__ Q, bf16* __restrict__ K, bf16* __restrict__ VT)
{
  __shared__ bf16 vt[64][72];
  const int t = threadIdx.x;
  const int bh = blockIdx.y, b = bh >> 4, h = bh & 15;
  const int sc = blockIdx.x * 64;
  const int sl = t >> 2, s = sc + sl;
  const int d0 = (t & 3) * 16;

  const size_t rowbase = (size_t)(b * 2048 + s) * 3072 + h * 64 + d0;
  const size_t obase = ((size_t)bh * 2048 + s) * 64 + d0;

  #pragma unroll
  for (int which = 0; which < 2; ++which) {
    const bf16* src = qkv + rowbase + which * 1024;
    bf16x8 v0 = *(const bf16x8*)src;
    bf16x8 v1 = *(const bf16x8*)(src + 8);
    if (d0 == 0) {
      bf16x8 r0, r1;
      #pragma unroll
      for (int j = 0; j < 8; ++j) {
        const float cs = freqs[s * 16 + j * 2];
        const float sn = freqs[s * 16 + j * 2 + 1];
        const float x1 = (float)v0[j], x2 = (float)v1[j];
        r0[j] = (bf16)(x1 * cs - x2 * sn);
        r1[j] = (bf16)(x1 * sn + x2 * cs);
      }
      v0 = r0; v1 = r1;
    }
    bf16* dst = (which == 0 ? Q : K) + obase;
    *(bf16x8*)dst = v0;
    *(bf16x8*)(dst + 8) = v1;
  }
  {
    const bf16* src = qkv + rowbase + 2048;
    bf16x8 v0 = *(const bf16x8*)src;
    bf16x8 v1 = *(const bf16x8*)(src + 8);
    #pragma unroll
    for (int j = 0; j < 8; ++j) { vt[sl][d0 + j] = v0[j]; vt[sl][d0 + 8 + j] = v1[j]; }
  }
  __syncthreads();
  {
    const int d = t >> 2;
    const int s0 = (t & 3) * 16;
    bf16x8 o0, o1;
    #pragma unroll
    for (int j = 0; j < 8; ++j) { o0[j] = vt[s0 + j][d]; o1[j] = vt[s0 + 8 + j][d]; }
    bf16* dst = VT + ((size_t)bh * 64 + d) * 2048 + sc + s0;
    *(bf16x8*)dst = o0;
    *(bf16x8*)(dst + 8) = o1;
  }
}

// ---------------- Causal flash attention (v3) ----------------
__global__ __launch_bounds__(512, 4) void attn_kernel(
    const bf16* __restrict__ Q, const bf16* __restrict__ Kg,
    const bf16* __restrict__ VTg, bf16* __restrict__ O, int ldO)
{
  __shared__ __align__(16) bf16 Ks[2][64][64];
  __shared__ __align__(16) bf16 Vs[2][64][64];
  __shared__ __align__(16) bf16 Ps[8][16][64];

  const int tid = threadIdx.x;
  const int lane = tid & 63, wave = tid >> 6;
  const int g = lane >> 4, c = lane & 15;
  const int L = blockIdx.x;
  const int half = L >> 8, r = L & 255;
  const int bh = (half << 4) | (r >> 4);
  const int qtile = half ? (15 - (r & 15)) : (r & 15);
  const int qw = qtile * 128 + wave * 16;

  const bf16* Qp = Q + (size_t)bh * 2048 * 64;
  const bf16* Kp = Kg + (size_t)bh * 2048 * 64;
  const bf16* Vp = VTg + (size_t)bh * 64 * 2048;

  const int srow = lane >> 3;
  const int schunk = (lane & 7) ^ srow;
  const int svr = wave * 8 + srow;
  bf16* kdst = &Ks[0][wave * 8][0];
  bf16* vdst = &Vs[0][wave * 8][0];
  const size_t kdelta = (size_t)64 * 64;

  bf16x8 qreg[2];
  {
    const float qs = 0.125f * 1.44269504f;
    bf16x8 t0 = *(const bf16x8*)&Qp[(size_t)(qw + c) * 64 + g * 8];
    bf16x8 t1 = *(const bf16x8*)&Qp[(size_t)(qw + c) * 64 + 32 + g * 8];
    #pragma unroll
    for (int j = 0; j < 8; ++j) {
      qreg[0][j] = (bf16)((float)t0[j] * qs);
      qreg[1][j] = (bf16)((float)t1[j] * qs);
    }
  }

  const int cq = c & 7;
  int fo[4][2];
  #pragma unroll
  for (int i = 0; i < 4; ++i)
    #pragma unroll
    for (int kk = 0; kk < 2; ++kk)
      fo[i][kk] = (i * 16 + c) * 64 + (((kk * 4 + g) ^ cq) << 3);
  bf16* pw[4];
  #pragma unroll
  for (int kf = 0; kf < 4; ++kf)
    pw[kf] = &Ps[wave][c][((((kf * 2 + (g >> 1)) ^ cq) << 3)) + ((g & 1) << 2)];
  const bf16* pr[2];
  #pragma unroll
  for (int kk = 0; kk < 2; ++kk)
    pr[kk] = &Ps[wave][c][((kk * 4 + g) ^ cq) << 3];
  const bf16* ks0 = &Ks[0][0][0];
  const bf16* vs0 = &Vs[0][0][0];

  f32x4 oacc[4] = {};
  float m_ = -1e30f, l_ = 0.0f;

  const int nkb = 2 * qtile + 2;
  gload_lds16(&Kp[(size_t)(svr) * 64 + schunk * 8], kdst);
  gload_lds16(&Vp[(size_t)(svr) * 2048 + schunk * 8], vdst);
  asm volatile("s_waitcnt vmcnt(0)" ::: "memory");
  __builtin_amdgcn_s_barrier();

  for (int kb = 0; kb < nkb; ++kb) {
    const int cur = kb & 1;
    const int kbase = kb * 64;
    if (kb + 1 < nkb) {
      const int nb = kbase + 64;
      gload_lds16(&Kp[(size_t)(nb + svr) * 64 + schunk * 8], kdst + (cur ^ 1) * kdelta);
      gload_lds16(&Vp[(size_t)(svr) * 2048 + nb + schunk * 8], vdst + (cur ^ 1) * kdelta);
    }
    if (kbase <= qw + 15) {
      const bf16* kt = ks0 + cur * kdelta;
      f32x4 st[4] = {};
      #pragma unroll
      for (int kf = 0; kf < 4; ++kf)
        #pragma unroll
        for (int kk = 0; kk < 2; ++kk)
          st[kf] = mfma16(*(const bf16x8*)(kt + fo[kf][kk]), qreg[kk], st[kf]);

      float v[16];
      if (kbase + 63 > qw) {
        const int qrel = qw + c - kbase;
        #pragma unroll
        for (int kf = 0; kf < 4; ++kf)
          #pragma unroll
          for (int rr = 0; rr < 4; ++rr)
            v[kf * 4 + rr] = (kf * 16 + 4 * g + rr <= qrel) ? st[kf][rr] : -1e30f;
      } else {
        #pragma unroll
        for (int kf = 0; kf < 4; ++kf)
          #pragma unroll
          for (int rr = 0; rr < 4; ++rr)
            v[kf * 4 + rr] = st[kf][rr];
      }
      float a0 = fmaxf(v[0], v[1]),  a1 = fmaxf(v[2], v[3]);
      float a2 = fmaxf(v[4], v[5]),  a3 = fmaxf(v[6], v[7]);
      float a4 = fmaxf(v[8], v[9]),  a5 = fmaxf(v[10], v[11]);
      float a6 = fmaxf(v[12], v[13]), a7 = fmaxf(v[14], v[15]);
      float b0 = fmaxf(a0, a1), b1 = fmaxf(a2, a3), b2_ = fmaxf(a4, a5), b3 = fmaxf(a6, a7);
      float tm = fmaxf(fmaxf(b0, b1), fmaxf(b2_, b3));
      tm = fmaxf(tm, __shfl_xor(tm, 16));
      tm = fmaxf(tm, __shfl_xor(tm, 32));
      if (__any(tm > m_ + 8.0f)) {
        const float mn = fmaxf(m_, tm);
        const float alpha = __builtin_amdgcn_exp2f(m_ - mn);
        m_ = mn;
        l_ *= alpha;
        #pragma unroll
        for (int df = 0; df < 4; ++df) {
          oacc[df][0] *= alpha; oacc[df][1] *= alpha;
          oacc[df][2] *= alpha; oacc[df][3] *= alpha;
        }
      }
      float ts = 0.0f;
      bf16 p[16];
      #pragma unroll
      for (int i = 0; i < 16; ++i) {
        const float pv = __builtin_amdgcn_exp2f(v[i] - m_);
        ts += pv;
        p[i] = (bf16)pv;
      }
      ts += __shfl_xor(ts, 16);
      ts += __shfl_xor(ts, 32);
      l_ += ts;
      #pragma unroll
      for (int kf = 0; kf < 4; ++kf) {
        bf16x4 pk = {p[kf * 4], p[kf * 4 + 1], p[kf * 4 + 2], p[kf * 4 + 3]};
        *(bf16x4*)pw[kf] = pk;
      }
      bf16x8 pfrag[2];
      pfrag[0] = *(const bf16x8*)pr[0];
      pfrag[1] = *(const bf16x8*)pr[1];
      const bf16* vt = vs0 + cur * kdelta;
      #pragma unroll
      for (int df = 0; df < 4; ++df)
        #pragma unroll
        for (int kk = 0; kk < 2; ++kk)
          oacc[df] = mfma16(*(const bf16x8*)(vt + fo[df][kk]), pfrag[kk], oacc[df]);
    }
    asm volatile("s_waitcnt vmcnt(0)" ::: "memory");
    __builtin_amdgcn_s_barrier();
  }

  const int b = bh >> 4, h = bh & 15;
  const float inv = 1.0f / l_;
  const int s = qw + c;
  #pragma unroll
  for (int df = 0; df < 4; ++df) {
    bf16x4 o;
    #pragma unroll
    for (int rr = 0; rr < 4; ++rr) o[rr] = (bf16)(oacc[df][rr] * inv);
    *(bf16x4*)&O[(size_t)(b * 2048 + s) * ldO + h * 64 + df * 16 + 4 * g] = o;
  }
}

// ---------------- host orchestration ----------------
extern "C" void kernel_launch(void* const* d_in, const int* in_sizes, int n_in,
                              void* d_out, int out_size, void* d_ws, size_t ws_size,
                              hipStream_t stream) {
  const float* x     = (const float*)d_in[0];
  const float* W_qkv = (const float*)d_in[2];
  const float* b_qkv = (const float*)d_in[3];
  const float* W_o   = (const float*)d_in[4];
  const float* b_o   = (const float*)d_in[5];
  const float* ln1w  = (const float*)d_in[6];
  const float* ln1b  = (const float*)d_in[7];
  const float* ln2w  = (const float*)d_in[8];
  const float* ln2b  = (const float*)d_in[9];
  const float* W1    = (const float*)d_in[10];
  const float* b1    = (const float*)d_in[11];
  const float* W2    = (const float*)d_in[12];
  const float* b2    = (const float*)d_in[13];
  const float* freqs = (const float*)d_in[14];
  float* out = (float*)d_out;

  char* ws = (char*)d_ws;
  const size_t MB = (size_t)1 << 20;
  bf16* h1   = (bf16*)(ws + 0 * MB);
  bf16* h2   = (bf16*)(ws + 8 * MB);
  bf16* wQKV = (bf16*)(ws + 16 * MB);
  bf16* wCat = (bf16*)(ws + 22 * MB);
  bf16* w1   = (bf16*)(ws + 32 * MB);
  bf16* qkv  = (bf16*)(ws + 40 * MB);
  bf16* Qb   = (bf16*)(ws + 64 * MB);
  bf16* Kb   = (bf16*)(ws + 72 * MB);
  bf16* VTb  = (bf16*)(ws + 80 * MB);
  bf16* A2   = (bf16*)(ws + 88 * MB);
  float* p0  = (float*)(ws + 0 * MB);
  float* p1  = (float*)(ws + 40 * MB);
  float* p2  = (float*)(ws + 64 * MB);

  ln_dual<<<4096, 256, 0, stream>>>(x, ln1w, ln1b, ln2w, ln2b, h1, h2);
  cast_f32_bf16<<<3072, 256, 0, stream>>>(W_qkv, wQKV, 786432);
  cast_f32_bf16<<<4096, 256, 0, stream>>>(W1, w1, 1048576);
  cast_row<<<1024, 256, 0, stream>>>(W_o, wCat, 5120, 1024);
  cast_row<<<1024, 256, 0, stream>>>(W2, wCat + 1024, 5120, 4096);

  gemm256<0><<<192, 512, 0, stream>>>(h1, wQKV, b_qkv, qkv,
                                      nullptr, nullptr, nullptr, nullptr,
                                      1024, 3072, 192, 12, 16);
  rope_reshape<<<dim3(32, 32), 256, 0, stream>>>(qkv, freqs, Qb, Kb, VTb);
  attn_kernel<<<512, 512, 0, stream>>>(Qb, Kb, VTb, A2, 5120);
  gemm256<1><<<256, 512, 0, stream>>>(h2, w1, b1, A2 + 1024,
                                      nullptr, nullptr, nullptr, nullptr,
                                      1024, 5120, 256, 16, 16);
  gemm256<2><<<256, 512, 0, stream>>>(A2, wCat, nullptr, p0,
                                      p1, p2, out, x,
                                      5120, 1024, 64, 4, 20);
  combine_out<<<4096, 256, 0, stream>>>(p0, p1, p2, b_o, b2, out);
}

// Round 7
// 246.457 us; speedup vs baseline: 1.0529x; 1.0513x over previous
//
#include <hip/hip_runtime.h>

#define DEV __device__ __forceinline__

typedef __bf16 bf16;
typedef bf16 bf16x4 __attribute__((ext_vector_type(4)));
typedef bf16 bf16x8 __attribute__((ext_vector_type(8)));
typedef float f32x4 __attribute__((ext_vector_type(4)));

DEV f32x4 mfma16(bf16x8 a, bf16x8 b, f32x4 c) {
  return __builtin_amdgcn_mfma_f32_16x16x32_bf16(a, b, c, 0, 0, 0);
}

DEV void gload_lds16(const bf16* g, bf16* l) {
  __builtin_amdgcn_global_load_lds((const __attribute__((address_space(1))) void*)g,
                                   (__attribute__((address_space(3))) void*)l, 16, 0, 0);
}

#define PH_BAR __builtin_amdgcn_s_barrier()
#define VM(NSTR) asm volatile("s_waitcnt vmcnt(" NSTR ")" ::: "memory")
#define WAITBAR(NSTR) asm volatile("s_waitcnt vmcnt(" NSTR ")\n\ts_barrier" ::: "memory")

// ---------------- LayerNorm (both param sets, shared mean/var) ----------------
__global__ __launch_bounds__(256) void ln_dual(
    const float* __restrict__ x,
    const float* __restrict__ w1, const float* __restrict__ b1,
    const float* __restrict__ w2, const float* __restrict__ b2,
    bf16* __restrict__ h1, bf16* __restrict__ h2)
{
  __shared__ float red[2][4];
  const int row = blockIdx.x, t = threadIdx.x;
  const int lane = t & 63, wave = t >> 6;
  const float4 v = ((const float4*)(x + (size_t)row * 1024))[t];
  float vv[4] = {v.x, v.y, v.z, v.w};
  float s = vv[0] + vv[1] + vv[2] + vv[3];
  float q = vv[0]*vv[0] + vv[1]*vv[1] + vv[2]*vv[2] + vv[3]*vv[3];
  #pragma unroll
  for (int o = 32; o; o >>= 1) { s += __shfl_xor(s, o); q += __shfl_xor(q, o); }
  if (lane == 0) { red[0][wave] = s; red[1][wave] = q; }
  __syncthreads();
  s = red[0][0] + red[0][1] + red[0][2] + red[0][3];
  q = red[1][0] + red[1][1] + red[1][2] + red[1][3];
  const float mu = s * (1.0f / 1024.0f);
  const float var = q * (1.0f / 1024.0f) - mu * mu;
  const float rs = rsqrtf(var + 1e-5f);
  bf16x4 o1, o2;
  #pragma unroll
  for (int j = 0; j < 4; ++j) {
    const int i = t * 4 + j;
    const float xh = (vv[j] - mu) * rs;
    o1[j] = (bf16)(xh * w1[i] + b1[i]);
    o2[j] = (bf16)(xh * w2[i] + b2[i]);
  }
  *(bf16x4*)&h1[(size_t)row * 1024 + t * 4] = o1;
  *(bf16x4*)&h2[(size_t)row * 1024 + t * 4] = o2;
}

// ---------------- f32 -> bf16 casts ----------------
__global__ __launch_bounds__(256) void cast_f32_bf16(
    const float* __restrict__ src, bf16* __restrict__ dst, int n4)
{
  const int i = blockIdx.x * 256 + threadIdx.x;
  if (i >= n4) return;
  const float4 v = ((const float4*)src)[i];
  bf16x4 o = {(bf16)v.x, (bf16)v.y, (bf16)v.z, (bf16)v.w};
  ((bf16x4*)dst)[i] = o;
}

__global__ __launch_bounds__(256) void cast_row(
    const float* __restrict__ src, bf16* __restrict__ dst, int ldd, int C)
{
  const int row = blockIdx.x;
  for (int off = threadIdx.x * 4; off < C; off += 1024) {
    const float4 v = *(const float4*)&src[(size_t)row * C + off];
    bf16x4 o = {(bf16)v.x, (bf16)v.y, (bf16)v.z, (bf16)v.w};
    *(bf16x4*)&dst[(size_t)row * ldd + off] = o;
  }
}

// ---------------- GEMM 256x256xBK64, 8 waves, m201-style 4-phase ----------------
// Phase = { ds_read frags ; issue 2 gload_lds ; barrier ; [sched_barrier]
//           setprio1 16xMFMA setprio0 [sched_barrier] ; (vmcnt(4) at ph1/ph3) ;
//           barrier }.
// Ledger (per thread, 2 loads/phase, issue order B00 B01 A00 A01 B10 B11 A10 A11):
//   wait vmcnt(4) at ph1 end drains B1*,A1* of CURRENT tile (read at ph2/ph3);
//   wait vmcnt(4) at ph3 end drains B00,B01,A00,A01 of NEXT tile (read ph0/ph1).
//   In-flight always 4-8, never drained to 0 in the main loop.
// LDS race safety: STG of tile t (targets t-1's read buffer) issues after t-1
// ph3's final barrier; by then every wave's ph3 ds_reads completed (MFMA data
// deps force lgkmcnt before the MFMAs that precede that barrier).
DEV bf16x8 ldfrag(const bf16* unit, int lr, int g) {
  return *(const bf16x8*)&unit[lr * 32 + ((g ^ ((lr >> 1) & 3)) << 3)];
}
DEV void read_bfr(const bf16* unit, int blr, int g, bf16x8 bfr[4]) {
  #pragma unroll
  for (int nj = 0; nj < 4; ++nj) bfr[nj] = ldfrag(unit, blr + nj * 16, g);
}
DEV void read_af(const bf16* unit, int alr, int g, bf16x8 af[4]) {
  #pragma unroll
  for (int ml = 0; ml < 4; ++ml) af[ml] = ldfrag(unit, alr + ml * 16, g);
}
DEV void do_mfma(const bf16x8 af[4], const bf16x8 bfr[4], f32x4 acc[8][4], int mh) {
  __builtin_amdgcn_sched_barrier(0);  // pin MFMA cluster inside its phase
  __builtin_amdgcn_s_setprio(1);
  #pragma unroll
  for (int ml = 0; ml < 4; ++ml)
    #pragma unroll
    for (int nj = 0; nj < 4; ++nj)
      acc[mh * 4 + ml][nj] = mfma16(af[ml], bfr[nj], acc[mh * 4 + ml][nj]);
  __builtin_amdgcn_s_setprio(0);
  __builtin_amdgcn_sched_barrier(0);
}

// EPI: 0 = bf16 + bias; 1 = bf16 gelu(acc+bias); 2 = f32 partial (split-K, no bias;
//      sk==0 partial additionally adds xadd[idx])
// VGPR note (R6): VGPR_Count=128 + acc in 128 AGPRs (unified file) = 256/wave,
// no spill; 2 waves/SIMD. Keep plain __launch_bounds__(512).
template <int EPI>
__global__ __launch_bounds__(512) void gemm256(
    const bf16* __restrict__ A, const bf16* __restrict__ B,
    const float* __restrict__ bias, void* __restrict__ Cv,
    float* __restrict__ P1, float* __restrict__ P2, float* __restrict__ P3,
    const float* __restrict__ xadd,
    int K, int ldc, int ntiles, int nbx, int nkt)
{
  __shared__ __align__(16) bf16 As[2][2][2][4096];
  __shared__ __align__(16) bf16 Bs[2][2][2][4096];
  const int tid = threadIdx.x;
  const int lane = tid & 63, wave = tid >> 6;
  const int wm = wave >> 2, wn = wave & 3;
  const int g = lane >> 4, c = lane & 15;
  const int cpx = gridDim.x >> 3;
  const int swz = ((int)blockIdx.x & 7) * cpx + ((int)blockIdx.x >> 3);
  const int tile = swz % ntiles;
  const int sk = swz / ntiles;
  const int bm = (tile / nbx) * 256, bn = (tile % nbx) * 256;

  const int slr = tid >> 2;
  const int sch = (tid & 3) ^ ((tid >> 3) & 3);
  const bf16* aU[2][2];
  const bf16* bU[2][2];
  {
    const bf16* a0 = A + (size_t)(bm + ((slr >> 6) * 128) + (slr & 63)) * K
                       + (size_t)sk * nkt * 64 + sch * 8;
    const bf16* b0 = B + (size_t)(bn + slr) * K + (size_t)sk * nkt * 64 + sch * 8;
    aU[0][0] = a0;            aU[0][1] = a0 + (size_t)64 * K;
    aU[1][0] = a0 + 32;       aU[1][1] = a0 + (size_t)64 * K + 32;
    bU[0][0] = b0;            bU[0][1] = b0 + (size_t)128 * K;
    bU[1][0] = b0 + 32;       bU[1][1] = b0 + (size_t)128 * K + 32;
  }
#define STG_A(bf_, kkh_, ub_, ko_) gload_lds16(aU[kkh_][ub_] + (ko_), &As[bf_][kkh_][ub_][wave * 512])
#define STG_B(bf_, kkh_, ub_, ko_) gload_lds16(bU[kkh_][ub_] + (ko_), &Bs[bf_][kkh_][ub_][wave * 512])

  f32x4 acc[8][4] = {};
  bf16x8 bfr[4], af[4];
  const int alr = (wm << 6) + c;
  const int blr = ((wn & 1) << 6) + c;
  const int bub = wn >> 1;

  // prologue: stage tile 0 (canonical order), wait first 4, barrier
  STG_B(0, 0, 0, 0); STG_B(0, 0, 1, 0); STG_A(0, 0, 0, 0); STG_A(0, 0, 1, 0);
  STG_B(0, 1, 0, 0); STG_B(0, 1, 1, 0); STG_A(0, 1, 0, 0); STG_A(0, 1, 1, 0);
  WAITBAR("4");

  for (int t = 0; t < nkt - 1; ++t) {
    const int buf = t & 1, nxt = buf ^ 1;
    const int ko = (t + 1) * 64;
    // ---- phase 0: kk=0, mh=0
    read_bfr(&Bs[buf][0][bub][0], blr, g, bfr);
    read_af(&As[buf][0][0][0], alr, g, af);
    STG_B(nxt, 0, 0, ko); STG_B(nxt, 0, 1, ko);
    PH_BAR;
    do_mfma(af, bfr, acc, 0);
    PH_BAR;
    // ---- phase 1: kk=0, mh=1 (bfr reused)
    read_af(&As[buf][0][1][0], alr, g, af);
    STG_A(nxt, 0, 0, ko); STG_A(nxt, 0, 1, ko);
    PH_BAR;
    do_mfma(af, bfr, acc, 1);
    VM("4");
    PH_BAR;
    // ---- phase 2: kk=1, mh=0
    read_bfr(&Bs[buf][1][bub][0], blr, g, bfr);
    read_af(&As[buf][1][0][0], alr, g, af);
    STG_B(nxt, 1, 0, ko); STG_B(nxt, 1, 1, ko);
    PH_BAR;
    do_mfma(af, bfr, acc, 0);
    PH_BAR;
    // ---- phase 3: kk=1, mh=1
    read_af(&As[buf][1][1][0], alr, g, af);
    STG_A(nxt, 1, 0, ko); STG_A(nxt, 1, 1, ko);
    PH_BAR;
    do_mfma(af, bfr, acc, 1);
    VM("4");
    PH_BAR;
  }
  {  // final K-tile: no staging; one vmcnt(0) drain at ph1
    const int buf = (nkt - 1) & 1;
    read_bfr(&Bs[buf][0][bub][0], blr, g, bfr);
    read_af(&As[buf][0][0][0], alr, g, af);
    PH_BAR;
    do_mfma(af, bfr, acc, 0);
    PH_BAR;
    read_af(&As[buf][0][1][0], alr, g, af);
    PH_BAR;
    do_mfma(af, bfr, acc, 1);
    VM("0");
    PH_BAR;
    read_bfr(&Bs[buf][1][bub][0], blr, g, bfr);
    read_af(&As[buf][1][0][0], alr, g, af);
    PH_BAR;
    do_mfma(af, bfr, acc, 0);
    PH_BAR;
    read_af(&As[buf][1][1][0], alr, g, af);
    PH_BAR;
    do_mfma(af, bfr, acc, 1);
  }
#undef STG_A
#undef STG_B

  float* Pp = nullptr;
  if constexpr (EPI == 2) Pp = (sk == 1) ? P1 : (sk == 2) ? P2 : (sk == 3) ? P3 : (float*)Cv;
  const int row0 = bm + wm * 128 + 4 * g;
  const int col0 = bn + wn * 64 + c;
  #pragma unroll
  for (int mi = 0; mi < 8; ++mi) {
    #pragma unroll
    for (int nj = 0; nj < 4; ++nj) {
      const int col = col0 + nj * 16;
      float bv = 0.0f;
      if constexpr (EPI < 2) bv = bias[col];
      #pragma unroll
      for (int r = 0; r < 4; ++r) {
        const size_t idx = (size_t)(row0 + mi * 16 + r) * ldc + col;
        float vo = acc[mi][nj][r] + bv;
        if constexpr (EPI == 0) {
          ((bf16*)Cv)[idx] = (bf16)vo;
        } else if constexpr (EPI == 1) {
          ((bf16*)Cv)[idx] = (bf16)(0.5f * vo * (1.0f + erff(vo * 0.70710678118f)));
        } else {
          if (sk == 0) vo += xadd[idx];
          Pp[idx] = vo;
        }
      }
    }
  }
}

// ---------------- combine: out = p3(=out) + p0 + p1 + p2 + b_o + b2 ----------------
__global__ __launch_bounds__(256) void combine_out(
    const float* __restrict__ p0, const float* __restrict__ p1,
    const float* __restrict__ p2,
    const float* __restrict__ bo, const float* __restrict__ b2,
    float* __restrict__ out)
{
  const int row = blockIdx.x, t = threadIdx.x;
  const size_t base = (size_t)row * 1024 + t * 4;
  float4 a = *(float4*)&out[base];
  const float4 v0 = *(const float4*)&p0[base];
  const float4 v1 = *(const float4*)&p1[base];
  const float4 v2 = *(const float4*)&p2[base];
  const float4 vb = *(const float4*)&bo[t * 4];
  const float4 vc = *(const float4*)&b2[t * 4];
  a.x += v0.x + v1.x + v2.x + vb.x + vc.x;
  a.y += v0.y + v1.y + v2.y + vb.y + vc.y;
  a.z += v0.z + v1.z + v2.z + vb.z + vc.z;
  a.w += v0.w + v1.w + v2.w + vb.w + vc.w;
  *(float4*)&out[base] = a;
}

// ---------------- RoPE + head reshape; also writes V^T ----------------
__global__ __launch_bounds__(256) void rope_reshape(
    const bf16* __restrict__ qkv, const float* __restrict__ freqs,
    bf16* __restrict__ Q, bf16* __restrict__ K, bf16* __restrict__ VT)
{
  __shared__ bf16 vt[64][72];
  const int t = threadIdx.x;
  const int bh = blockIdx.y, b = bh >> 4, h = bh & 15;
  const int sc = blockIdx.x * 64;
  const int sl = t >> 2, s = sc + sl;
  const int d0 = (t & 3) * 16;

  const size_t rowbase = (size_t)(b * 2048 + s) * 3072 + h * 64 + d0;
  const size_t obase = ((size_t)bh * 2048 + s) * 64 + d0;

  #pragma unroll
  for (int which = 0; which < 2; ++which) {
    const bf16* src = qkv + rowbase + which * 1024;
    bf16x8 v0 = *(const bf16x8*)src;
    bf16x8 v1 = *(const bf16x8*)(src + 8);
    if (d0 == 0) {
      bf16x8 r0, r1;
      #pragma unroll
      for (int j = 0; j < 8; ++j) {
        const float cs = freqs[s * 16 + j * 2];
        const float sn = freqs[s * 16 + j * 2 + 1];
        const float x1 = (float)v0[j], x2 = (float)v1[j];
        r0[j] = (bf16)(x1 * cs - x2 * sn);
        r1[j] = (bf16)(x1 * sn + x2 * cs);
      }
      v0 = r0; v1 = r1;
    }
    bf16* dst = (which == 0 ? Q : K) + obase;
    *(bf16x8*)dst = v0;
    *(bf16x8*)(dst + 8) = v1;
  }
  {
    const bf16* src = qkv + rowbase + 2048;
    bf16x8 v0 = *(const bf16x8*)src;
    bf16x8 v1 = *(const bf16x8*)(src + 8);
    #pragma unroll
    for (int j = 0; j < 8; ++j) { vt[sl][d0 + j] = v0[j]; vt[sl][d0 + 8 + j] = v1[j]; }
  }
  __syncthreads();
  {
    const int d = t >> 2;
    const int s0 = (t & 3) * 16;
    bf16x8 o0, o1;
    #pragma unroll
    for (int j = 0; j < 8; ++j) { o0[j] = vt[s0 + j][d]; o1[j] = vt[s0 + 8 + j][d]; }
    bf16* dst = VT + ((size_t)bh * 64 + d) * 2048 + sc + s0;
    *(bf16x8*)dst = o0;
    *(bf16x8*)(dst + 8) = o1;
  }
}

// ---------------- Causal flash attention (v3) ----------------
__global__ __launch_bounds__(512, 4) void attn_kernel(
    const bf16* __restrict__ Q, const bf16* __restrict__ Kg,
    const bf16* __restrict__ VTg, bf16* __restrict__ O, int ldO)
{
  __shared__ __align__(16) bf16 Ks[2][64][64];
  __shared__ __align__(16) bf16 Vs[2][64][64];
  __shared__ __align__(16) bf16 Ps[8][16][64];

  const int tid = threadIdx.x;
  const int lane = tid & 63, wave = tid >> 6;
  const int g = lane >> 4, c = lane & 15;
  const int L = blockIdx.x;
  const int half = L >> 8, r = L & 255;
  const int bh = (half << 4) | (r >> 4);
  const int qtile = half ? (15 - (r & 15)) : (r & 15);
  const int qw = qtile * 128 + wave * 16;

  const bf16* Qp = Q + (size_t)bh * 2048 * 64;
  const bf16* Kp = Kg + (size_t)bh * 2048 * 64;
  const bf16* Vp = VTg + (size_t)bh * 64 * 2048;

  const int srow = lane >> 3;
  const int schunk = (lane & 7) ^ srow;
  const int svr = wave * 8 + srow;
  bf16* kdst = &Ks[0][wave * 8][0];
  bf16* vdst = &Vs[0][wave * 8][0];
  const size_t kdelta = (size_t)64 * 64;

  bf16x8 qreg[2];
  {
    const float qs = 0.125f * 1.44269504f;
    bf16x8 t0 = *(const bf16x8*)&Qp[(size_t)(qw + c) * 64 + g * 8];
    bf16x8 t1 = *(const bf16x8*)&Qp[(size_t)(qw + c) * 64 + 32 + g * 8];
    #pragma unroll
    for (int j = 0; j < 8; ++j) {
      qreg[0][j] = (bf16)((float)t0[j] * qs);
      qreg[1][j] = (bf16)((float)t1[j] * qs);
    }
  }

  const int cq = c & 7;
  int fo[4][2];
  #pragma unroll
  for (int i = 0; i < 4; ++i)
    #pragma unroll
    for (int kk = 0; kk < 2; ++kk)
      fo[i][kk] = (i * 16 + c) * 64 + (((kk * 4 + g) ^ cq) << 3);
  bf16* pw[4];
  #pragma unroll
  for (int kf = 0; kf < 4; ++kf)
    pw[kf] = &Ps[wave][c][((((kf * 2 + (g >> 1)) ^ cq) << 3)) + ((g & 1) << 2)];
  const bf16* pr[2];
  #pragma unroll
  for (int kk = 0; kk < 2; ++kk)
    pr[kk] = &Ps[wave][c][((kk * 4 + g) ^ cq) << 3];
  const bf16* ks0 = &Ks[0][0][0];
  const bf16* vs0 = &Vs[0][0][0];

  f32x4 oacc[4] = {};
  float m_ = -1e30f, l_ = 0.0f;

  const int nkb = 2 * qtile + 2;
  gload_lds16(&Kp[(size_t)(svr) * 64 + schunk * 8], kdst);
  gload_lds16(&Vp[(size_t)(svr) * 2048 + schunk * 8], vdst);
  asm volatile("s_waitcnt vmcnt(0)" ::: "memory");
  __builtin_amdgcn_s_barrier();

  for (int kb = 0; kb < nkb; ++kb) {
    const int cur = kb & 1;
    const int kbase = kb * 64;
    if (kb + 1 < nkb) {
      const int nb = kbase + 64;
      gload_lds16(&Kp[(size_t)(nb + svr) * 64 + schunk * 8], kdst + (cur ^ 1) * kdelta);
      gload_lds16(&Vp[(size_t)(svr) * 2048 + nb + schunk * 8], vdst + (cur ^ 1) * kdelta);
    }
    if (kbase <= qw + 15) {
      const bf16* kt = ks0 + cur * kdelta;
      f32x4 st[4] = {};
      #pragma unroll
      for (int kf = 0; kf < 4; ++kf)
        #pragma unroll
        for (int kk = 0; kk < 2; ++kk)
          st[kf] = mfma16(*(const bf16x8*)(kt + fo[kf][kk]), qreg[kk], st[kf]);

      float v[16];
      if (kbase + 63 > qw) {
        const int qrel = qw + c - kbase;
        #pragma unroll
        for (int kf = 0; kf < 4; ++kf)
          #pragma unroll
          for (int rr = 0; rr < 4; ++rr)
            v[kf * 4 + rr] = (kf * 16 + 4 * g + rr <= qrel) ? st[kf][rr] : -1e30f;
      } else {
        #pragma unroll
        for (int kf = 0; kf < 4; ++kf)
          #pragma unroll
          for (int rr = 0; rr < 4; ++rr)
            v[kf * 4 + rr] = st[kf][rr];
      }
      float a0 = fmaxf(v[0], v[1]),  a1 = fmaxf(v[2], v[3]);
      float a2 = fmaxf(v[4], v[5]),  a3 = fmaxf(v[6], v[7]);
      float a4 = fmaxf(v[8], v[9]),  a5 = fmaxf(v[10], v[11]);
      float a6 = fmaxf(v[12], v[13]), a7 = fmaxf(v[14], v[15]);
      float b0 = fmaxf(a0, a1), b1 = fmaxf(a2, a3), b2_ = fmaxf(a4, a5), b3 = fmaxf(a6, a7);
      float tm = fmaxf(fmaxf(b0, b1), fmaxf(b2_, b3));
      tm = fmaxf(tm, __shfl_xor(tm, 16));
      tm = fmaxf(tm, __shfl_xor(tm, 32));
      if (__any(tm > m_ + 8.0f)) {
        const float mn = fmaxf(m_, tm);
        const float alpha = __builtin_amdgcn_exp2f(m_ - mn);
        m_ = mn;
        l_ *= alpha;
        #pragma unroll
        for (int df = 0; df < 4; ++df) {
          oacc[df][0] *= alpha; oacc[df][1] *= alpha;
          oacc[df][2] *= alpha; oacc[df][3] *= alpha;
        }
      }
      float ts = 0.0f;
      bf16 p[16];
      #pragma unroll
      for (int i = 0; i < 16; ++i) {
        const float pv = __builtin_amdgcn_exp2f(v[i] - m_);
        ts += pv;
        p[i] = (bf16)pv;
      }
      ts += __shfl_xor(ts, 16);
      ts += __shfl_xor(ts, 32);
      l_ += ts;
      #pragma unroll
      for (int kf = 0; kf < 4; ++kf) {
        bf16x4 pk = {p[kf * 4], p[kf * 4 + 1], p[kf * 4 + 2], p[kf * 4 + 3]};
        *(bf16x4*)pw[kf] = pk;
      }
      bf16x8 pfrag[2];
      pfrag[0] = *(const bf16x8*)pr[0];
      pfrag[1] = *(const bf16x8*)pr[1];
      const bf16* vt = vs0 + cur * kdelta;
      #pragma unroll
      for (int df = 0; df < 4; ++df)
        #pragma unroll
        for (int kk = 0; kk < 2; ++kk)
          oacc[df] = mfma16(*(const bf16x8*)(vt + fo[df][kk]), pfrag[kk], oacc[df]);
    }
    asm volatile("s_waitcnt vmcnt(0)" ::: "memory");
    __builtin_amdgcn_s_barrier();
  }

  const int b = bh >> 4, h = bh & 15;
  const float inv = 1.0f / l_;
  const int s = qw + c;
  #pragma unroll
  for (int df = 0; df < 4; ++df) {
    bf16x4 o;
    #pragma unroll
    for (int rr = 0; rr < 4; ++rr) o[rr] = (bf16)(oacc[df][rr] * inv);
    *(bf16x4*)&O[(size_t)(b * 2048 + s) * ldO + h * 64 + df * 16 + 4 * g] = o;
  }
}

// ---------------- host orchestration ----------------
extern "C" void kernel_launch(void* const* d_in, const int* in_sizes, int n_in,
                              void* d_out, int out_size, void* d_ws, size_t ws_size,
                              hipStream_t stream) {
  const float* x     = (const float*)d_in[0];
  const float* W_qkv = (const float*)d_in[2];
  const float* b_qkv = (const float*)d_in[3];
  const float* W_o   = (const float*)d_in[4];
  const float* b_o   = (const float*)d_in[5];
  const float* ln1w  = (const float*)d_in[6];
  const float* ln1b  = (const float*)d_in[7];
  const float* ln2w  = (const float*)d_in[8];
  const float* ln2b  = (const float*)d_in[9];
  const float* W1    = (const float*)d_in[10];
  const float* b1    = (const float*)d_in[11];
  const float* W2    = (const float*)d_in[12];
  const float* b2    = (const float*)d_in[13];
  const float* freqs = (const float*)d_in[14];
  float* out = (float*)d_out;

  char* ws = (char*)d_ws;
  const size_t MB = (size_t)1 << 20;
  bf16* h1   = (bf16*)(ws + 0 * MB);
  bf16* h2   = (bf16*)(ws + 8 * MB);
  bf16* wQKV = (bf16*)(ws + 16 * MB);
  bf16* wCat = (bf16*)(ws + 22 * MB);
  bf16* w1   = (bf16*)(ws + 32 * MB);
  bf16* qkv  = (bf16*)(ws + 40 * MB);
  bf16* Qb   = (bf16*)(ws + 64 * MB);
  bf16* Kb   = (bf16*)(ws + 72 * MB);
  bf16* VTb  = (bf16*)(ws + 80 * MB);
  bf16* A2   = (bf16*)(ws + 88 * MB);
  float* p0  = (float*)(ws + 0 * MB);
  float* p1  = (float*)(ws + 40 * MB);
  float* p2  = (float*)(ws + 64 * MB);

  ln_dual<<<4096, 256, 0, stream>>>(x, ln1w, ln1b, ln2w, ln2b, h1, h2);
  cast_f32_bf16<<<3072, 256, 0, stream>>>(W_qkv, wQKV, 786432);
  cast_f32_bf16<<<4096, 256, 0, stream>>>(W1, w1, 1048576);
  cast_row<<<1024, 256, 0, stream>>>(W_o, wCat, 5120, 1024);
  cast_row<<<1024, 256, 0, stream>>>(W2, wCat + 1024, 5120, 4096);

  gemm256<0><<<192, 512, 0, stream>>>(h1, wQKV, b_qkv, qkv,
                                      nullptr, nullptr, nullptr, nullptr,
                                      1024, 3072, 192, 12, 16);
  rope_reshape<<<dim3(32, 32), 256, 0, stream>>>(qkv, freqs, Qb, Kb, VTb);
  attn_kernel<<<512, 512, 0, stream>>>(Qb, Kb, VTb, A2, 5120);
  gemm256<1><<<256, 512, 0, stream>>>(h2, w1, b1, A2 + 1024,
                                      nullptr, nullptr, nullptr, nullptr,
                                      1024, 5120, 256, 16, 16);
  gemm256<2><<<256, 512, 0, stream>>>(A2, wCat, nullptr, p0,
                                      p1, p2, out, x,
                                      5120, 1024, 64, 4, 20);
  combine_out<<<4096, 256, 0, stream>>>(p0, p1, p2, b_o, b2, out);
}

// Round 8
// 225.159 us; speedup vs baseline: 1.1525x; 1.0946x over previous
//
#include <hip/hip_runtime.h>

#define DEV __device__ __forceinline__

typedef __bf16 bf16;
typedef bf16 bf16x4 __attribute__((ext_vector_type(4)));
typedef bf16 bf16x8 __attribute__((ext_vector_type(8)));
typedef float f32x4 __attribute__((ext_vector_type(4)));

DEV f32x4 mfma16(bf16x8 a, bf16x8 b, f32x4 c) {
  return __builtin_amdgcn_mfma_f32_16x16x32_bf16(a, b, c, 0, 0, 0);
}

DEV void gload_lds16(const bf16* g, bf16* l) {
  __builtin_amdgcn_global_load_lds((const __attribute__((address_space(1))) void*)g,
                                   (__attribute__((address_space(3))) void*)l, 16, 0, 0);
}

#define PH_BAR __builtin_amdgcn_s_barrier()
#define VM(NSTR) asm volatile("s_waitcnt vmcnt(" NSTR ")" ::: "memory")
#define WAITBAR(NSTR) asm volatile("s_waitcnt vmcnt(" NSTR ")\n\ts_barrier" ::: "memory")

// ---------------- LayerNorm (both param sets, shared mean/var) ----------------
__global__ __launch_bounds__(256) void ln_dual(
    const float* __restrict__ x,
    const float* __restrict__ w1, const float* __restrict__ b1,
    const float* __restrict__ w2, const float* __restrict__ b2,
    bf16* __restrict__ h1, bf16* __restrict__ h2)
{
  __shared__ float red[2][4];
  const int row = blockIdx.x, t = threadIdx.x;
  const int lane = t & 63, wave = t >> 6;
  const float4 v = ((const float4*)(x + (size_t)row * 1024))[t];
  float vv[4] = {v.x, v.y, v.z, v.w};
  float s = vv[0] + vv[1] + vv[2] + vv[3];
  float q = vv[0]*vv[0] + vv[1]*vv[1] + vv[2]*vv[2] + vv[3]*vv[3];
  #pragma unroll
  for (int o = 32; o; o >>= 1) { s += __shfl_xor(s, o); q += __shfl_xor(q, o); }
  if (lane == 0) { red[0][wave] = s; red[1][wave] = q; }
  __syncthreads();
  s = red[0][0] + red[0][1] + red[0][2] + red[0][3];
  q = red[1][0] + red[1][1] + red[1][2] + red[1][3];
  const float mu = s * (1.0f / 1024.0f);
  const float var = q * (1.0f / 1024.0f) - mu * mu;
  const float rs = rsqrtf(var + 1e-5f);
  bf16x4 o1, o2;
  #pragma unroll
  for (int j = 0; j < 4; ++j) {
    const int i = t * 4 + j;
    const float xh = (vv[j] - mu) * rs;
    o1[j] = (bf16)(xh * w1[i] + b1[i]);
    o2[j] = (bf16)(xh * w2[i] + b2[i]);
  }
  *(bf16x4*)&h1[(size_t)row * 1024 + t * 4] = o1;
  *(bf16x4*)&h2[(size_t)row * 1024 + t * 4] = o2;
}

// ---------------- f32 -> bf16 casts ----------------
__global__ __launch_bounds__(256) void cast_f32_bf16(
    const float* __restrict__ src, bf16* __restrict__ dst, int n4)
{
  const int i = blockIdx.x * 256 + threadIdx.x;
  if (i >= n4) return;
  const float4 v = ((const float4*)src)[i];
  bf16x4 o = {(bf16)v.x, (bf16)v.y, (bf16)v.z, (bf16)v.w};
  ((bf16x4*)dst)[i] = o;
}

__global__ __launch_bounds__(256) void cast_row(
    const float* __restrict__ src, bf16* __restrict__ dst, int ldd, int C)
{
  const int row = blockIdx.x;
  for (int off = threadIdx.x * 4; off < C; off += 1024) {
    const float4 v = *(const float4*)&src[(size_t)row * C + off];
    bf16x4 o = {(bf16)v.x, (bf16)v.y, (bf16)v.z, (bf16)v.w};
    *(bf16x4*)&dst[(size_t)row * ldd + off] = o;
  }
}

// ---------------- GEMM 256x256xBK64, 8 waves, m201-style 4-phase ----------------
// (see R7 notes; R8: sched_barrier(0) removed per m141 — order-pinning defeats
// the compiler's own scheduling. setprio kept (T5).)
DEV bf16x8 ldfrag(const bf16* unit, int lr, int g) {
  return *(const bf16x8*)&unit[lr * 32 + ((g ^ ((lr >> 1) & 3)) << 3)];
}
DEV void read_bfr(const bf16* unit, int blr, int g, bf16x8 bfr[4]) {
  #pragma unroll
  for (int nj = 0; nj < 4; ++nj) bfr[nj] = ldfrag(unit, blr + nj * 16, g);
}
DEV void read_af(const bf16* unit, int alr, int g, bf16x8 af[4]) {
  #pragma unroll
  for (int ml = 0; ml < 4; ++ml) af[ml] = ldfrag(unit, alr + ml * 16, g);
}
DEV void do_mfma(const bf16x8 af[4], const bf16x8 bfr[4], f32x4 acc[8][4], int mh) {
  __builtin_amdgcn_s_setprio(1);
  #pragma unroll
  for (int ml = 0; ml < 4; ++ml)
    #pragma unroll
    for (int nj = 0; nj < 4; ++nj)
      acc[mh * 4 + ml][nj] = mfma16(af[ml], bfr[nj], acc[mh * 4 + ml][nj]);
  __builtin_amdgcn_s_setprio(0);
}

// EPI: 0 = bf16 + bias; 1 = bf16 gelu(acc+bias); 2 = f32 partial (split-K, no bias)
template <int EPI>
__global__ __launch_bounds__(512) void gemm256(
    const bf16* __restrict__ A, const bf16* __restrict__ B,
    const float* __restrict__ bias, void* __restrict__ Cv,
    float* __restrict__ P1, float* __restrict__ P2, float* __restrict__ P3,
    int K, int ldc, int ntiles, int nbx, int nkt)
{
  __shared__ __align__(16) bf16 As[2][2][2][4096];
  __shared__ __align__(16) bf16 Bs[2][2][2][4096];
  const int tid = threadIdx.x;
  const int lane = tid & 63, wave = tid >> 6;
  const int wm = wave >> 2, wn = wave & 3;
  const int g = lane >> 4, c = lane & 15;
  const int cpx = gridDim.x >> 3;
  const int swz = ((int)blockIdx.x & 7) * cpx + ((int)blockIdx.x >> 3);
  const int tile = swz % ntiles;
  const int sk = swz / ntiles;
  const int bm = (tile / nbx) * 256, bn = (tile % nbx) * 256;

  const int slr = tid >> 2;
  const int sch = (tid & 3) ^ ((tid >> 3) & 3);
  const bf16* aU[2][2];
  const bf16* bU[2][2];
  {
    const bf16* a0 = A + (size_t)(bm + ((slr >> 6) * 128) + (slr & 63)) * K
                       + (size_t)sk * nkt * 64 + sch * 8;
    const bf16* b0 = B + (size_t)(bn + slr) * K + (size_t)sk * nkt * 64 + sch * 8;
    aU[0][0] = a0;            aU[0][1] = a0 + (size_t)64 * K;
    aU[1][0] = a0 + 32;       aU[1][1] = a0 + (size_t)64 * K + 32;
    bU[0][0] = b0;            bU[0][1] = b0 + (size_t)128 * K;
    bU[1][0] = b0 + 32;       bU[1][1] = b0 + (size_t)128 * K + 32;
  }
#define STG_A(bf_, kkh_, ub_, ko_) gload_lds16(aU[kkh_][ub_] + (ko_), &As[bf_][kkh_][ub_][wave * 512])
#define STG_B(bf_, kkh_, ub_, ko_) gload_lds16(bU[kkh_][ub_] + (ko_), &Bs[bf_][kkh_][ub_][wave * 512])

  f32x4 acc[8][4] = {};
  bf16x8 bfr[4], af[4];
  const int alr = (wm << 6) + c;
  const int blr = ((wn & 1) << 6) + c;
  const int bub = wn >> 1;

  STG_B(0, 0, 0, 0); STG_B(0, 0, 1, 0); STG_A(0, 0, 0, 0); STG_A(0, 0, 1, 0);
  STG_B(0, 1, 0, 0); STG_B(0, 1, 1, 0); STG_A(0, 1, 0, 0); STG_A(0, 1, 1, 0);
  WAITBAR("4");

  for (int t = 0; t < nkt - 1; ++t) {
    const int buf = t & 1, nxt = buf ^ 1;
    const int ko = (t + 1) * 64;
    // ---- phase 0: kk=0, mh=0
    read_bfr(&Bs[buf][0][bub][0], blr, g, bfr);
    read_af(&As[buf][0][0][0], alr, g, af);
    STG_B(nxt, 0, 0, ko); STG_B(nxt, 0, 1, ko);
    PH_BAR;
    do_mfma(af, bfr, acc, 0);
    PH_BAR;
    // ---- phase 1: kk=0, mh=1 (bfr reused)
    read_af(&As[buf][0][1][0], alr, g, af);
    STG_A(nxt, 0, 0, ko); STG_A(nxt, 0, 1, ko);
    PH_BAR;
    do_mfma(af, bfr, acc, 1);
    VM("4");
    PH_BAR;
    // ---- phase 2: kk=1, mh=0
    read_bfr(&Bs[buf][1][bub][0], blr, g, bfr);
    read_af(&As[buf][1][0][0], alr, g, af);
    STG_B(nxt, 1, 0, ko); STG_B(nxt, 1, 1, ko);
    PH_BAR;
    do_mfma(af, bfr, acc, 0);
    PH_BAR;
    // ---- phase 3: kk=1, mh=1
    read_af(&As[buf][1][1][0], alr, g, af);
    STG_A(nxt, 1, 0, ko); STG_A(nxt, 1, 1, ko);
    PH_BAR;
    do_mfma(af, bfr, acc, 1);
    VM("4");
    PH_BAR;
  }
  {  // final K-tile: no staging
    const int buf = (nkt - 1) & 1;
    read_bfr(&Bs[buf][0][bub][0], blr, g, bfr);
    read_af(&As[buf][0][0][0], alr, g, af);
    PH_BAR;
    do_mfma(af, bfr, acc, 0);
    PH_BAR;
    read_af(&As[buf][0][1][0], alr, g, af);
    PH_BAR;
    do_mfma(af, bfr, acc, 1);
    VM("0");
    PH_BAR;
    read_bfr(&Bs[buf][1][bub][0], blr, g, bfr);
    read_af(&As[buf][1][0][0], alr, g, af);
    PH_BAR;
    do_mfma(af, bfr, acc, 0);
    PH_BAR;
    read_af(&As[buf][1][1][0], alr, g, af);
    PH_BAR;
    do_mfma(af, bfr, acc, 1);
  }
#undef STG_A
#undef STG_B

  float* Pp = nullptr;
  if constexpr (EPI == 2) Pp = (sk == 1) ? P1 : (sk == 2) ? P2 : (sk == 3) ? P3 : (float*)Cv;
  const int row0 = bm + wm * 128 + 4 * g;
  const int col0 = bn + wn * 64 + c;
  #pragma unroll
  for (int mi = 0; mi < 8; ++mi) {
    #pragma unroll
    for (int nj = 0; nj < 4; ++nj) {
      const int col = col0 + nj * 16;
      float bv = 0.0f;
      if constexpr (EPI < 2) bv = bias[col];
      #pragma unroll
      for (int r = 0; r < 4; ++r) {
        const size_t idx = (size_t)(row0 + mi * 16 + r) * ldc + col;
        float vo = acc[mi][nj][r] + bv;
        if constexpr (EPI == 0) {
          ((bf16*)Cv)[idx] = (bf16)vo;
        } else if constexpr (EPI == 1) {
          ((bf16*)Cv)[idx] = (bf16)(0.5f * vo * (1.0f + erff(vo * 0.70710678118f)));
        } else {
          Pp[idx] = vo;
        }
      }
    }
  }
}

// ---------------- combine: out = p3(=out) + p0 + p1 + p2 + x + b_o + b2 ----------------
__global__ __launch_bounds__(256) void combine_out(
    const float* __restrict__ p0, const float* __restrict__ p1,
    const float* __restrict__ p2, const float* __restrict__ x,
    const float* __restrict__ bo, const float* __restrict__ b2,
    float* __restrict__ out)
{
  const int row = blockIdx.x, t = threadIdx.x;
  const size_t base = (size_t)row * 1024 + t * 4;
  float4 a = *(float4*)&out[base];
  const float4 v0 = *(const float4*)&p0[base];
  const float4 v1 = *(const float4*)&p1[base];
  const float4 v2 = *(const float4*)&p2[base];
  const float4 vx = *(const float4*)&x[base];
  const float4 vb = *(const float4*)&bo[t * 4];
  const float4 vc = *(const float4*)&b2[t * 4];
  a.x += v0.x + v1.x + v2.x + vx.x + vb.x + vc.x;
  a.y += v0.y + v1.y + v2.y + vx.y + vb.y + vc.y;
  a.z += v0.z + v1.z + v2.z + vx.z + vb.z + vc.z;
  a.w += v0.w + v1.w + v2.w + vx.w + vb.w + vc.w;
  *(float4*)&out[base] = a;
}

// ---------------- RoPE + head reshape; also writes V^T ----------------
__global__ __launch_bounds__(256) void rope_reshape(
    const bf16* __restrict__ qkv, const float* __restrict__ freqs,
    bf16* __restrict__ Q, bf16* __restrict__ K, bf16* __restrict__ VT)
{
  __shared__ bf16 vt[64][72];
  const int t = threadIdx.x;
  const int bh = blockIdx.y, b = bh >> 4, h = bh & 15;
  const int sc = blockIdx.x * 64;
  const int sl = t >> 2, s = sc + sl;
  const int d0 = (t & 3) * 16;

  const size_t rowbase = (size_t)(b * 2048 + s) * 3072 + h * 64 + d0;
  const size_t obase = ((size_t)bh * 2048 + s) * 64 + d0;

  #pragma unroll
  for (int which = 0; which < 2; ++which) {
    const bf16* src = qkv + rowbase + which * 1024;
    bf16x8 v0 = *(const bf16x8*)src;
    bf16x8 v1 = *(const bf16x8*)(src + 8);
    if (d0 == 0) {
      bf16x8 r0, r1;
      #pragma unroll
      for (int j = 0; j < 8; ++j) {
        const float cs = freqs[s * 16 + j * 2];
        const float sn = freqs[s * 16 + j * 2 + 1];
        const float x1 = (float)v0[j], x2 = (float)v1[j];
        r0[j] = (bf16)(x1 * cs - x2 * sn);
        r1[j] = (bf16)(x1 * sn + x2 * cs);
      }
      v0 = r0; v1 = r1;
    }
    bf16* dst = (which == 0 ? Q : K) + obase;
    *(bf16x8*)dst = v0;
    *(bf16x8*)(dst + 8) = v1;
  }
  {
    const bf16* src = qkv + rowbase + 2048;
    bf16x8 v0 = *(const bf16x8*)src;
    bf16x8 v1 = *(const bf16x8*)(src + 8);
    #pragma unroll
    for (int j = 0; j < 8; ++j) { vt[sl][d0 + j] = v0[j]; vt[sl][d0 + 8 + j] = v1[j]; }
  }
  __syncthreads();
  {
    const int d = t >> 2;
    const int s0 = (t & 3) * 16;
    bf16x8 o0, o1;
    #pragma unroll
    for (int j = 0; j < 8; ++j) { o0[j] = vt[s0 + j][d]; o1[j] = vt[s0 + 8 + j][d]; }
    bf16* dst = VT + ((size_t)bh * 64 + d) * 2048 + sc + s0;
    *(bf16x8*)dst = o0;
    *(bf16x8*)(dst + 8) = o1;
  }
}

// ---------------- Causal flash attention (v4) ----------------
// R8: 3-buffer K/V pipeline with counted vmcnt(2) — next-next tile's loads stay
// in flight across barriers (T3/T4); LDS 64KB -> 2 blocks/CU (16 waves);
// setprio around MFMA clusters (T5, attn-positive per m191).
__global__ __launch_bounds__(512) void attn_kernel(
    const bf16* __restrict__ Q, const bf16* __restrict__ Kg,
    const bf16* __restrict__ VTg, bf16* __restrict__ O, int ldO)
{
  __shared__ __align__(16) bf16 Ks[3][64][64];
  __shared__ __align__(16) bf16 Vs[3][64][64];
  __shared__ __align__(16) bf16 Ps[8][16][64];

  const int tid = threadIdx.x;
  const int lane = tid & 63, wave = tid >> 6;
  const int g = lane >> 4, c = lane & 15;
  const int L = blockIdx.x;
  const int half = L >> 8, r = L & 255;
  const int bh = (half << 4) | (r >> 4);
  const int qtile = half ? (15 - (r & 15)) : (r & 15);
  const int qw = qtile * 128 + wave * 16;

  const bf16* Qp = Q + (size_t)bh * 2048 * 64;
  const bf16* Kp = Kg + (size_t)bh * 2048 * 64;
  const bf16* Vp = VTg + (size_t)bh * 64 * 2048;

  const int srow = lane >> 3;
  const int schunk = (lane & 7) ^ srow;
  const int svr = wave * 8 + srow;
  const size_t kdelta = (size_t)64 * 64;

  bf16x8 qreg[2];
  {
    const float qs = 0.125f * 1.44269504f;
    bf16x8 t0 = *(const bf16x8*)&Qp[(size_t)(qw + c) * 64 + g * 8];
    bf16x8 t1 = *(const bf16x8*)&Qp[(size_t)(qw + c) * 64 + 32 + g * 8];
    #pragma unroll
    for (int j = 0; j < 8; ++j) {
      qreg[0][j] = (bf16)((float)t0[j] * qs);
      qreg[1][j] = (bf16)((float)t1[j] * qs);
    }
  }

  const int cq = c & 7;
  int fo[4][2];
  #pragma unroll
  for (int i = 0; i < 4; ++i)
    #pragma unroll
    for (int kk = 0; kk < 2; ++kk)
      fo[i][kk] = (i * 16 + c) * 64 + (((kk * 4 + g) ^ cq) << 3);
  bf16* pw[4];
  #pragma unroll
  for (int kf = 0; kf < 4; ++kf)
    pw[kf] = &Ps[wave][c][((((kf * 2 + (g >> 1)) ^ cq) << 3)) + ((g & 1) << 2)];
  const bf16* pr[2];
  #pragma unroll
  for (int kk = 0; kk < 2; ++kk)
    pr[kk] = &Ps[wave][c][((kk * 4 + g) ^ cq) << 3];
  const bf16* ks0 = &Ks[0][0][0];
  const bf16* vs0 = &Vs[0][0][0];

  f32x4 oacc[4] = {};
  float m_ = -1e30f, l_ = 0.0f;

  const int nkb = 2 * qtile + 2;  // >= 2 always
  // stage tile j into buffer j%3 (2 loads per thread)
#define STAGE(j_, b3_) do {                                                        \
    gload_lds16(&Kp[(size_t)((j_) * 64 + svr) * 64 + schunk * 8], &Ks[b3_][wave * 8][0]); \
    gload_lds16(&Vp[(size_t)svr * 2048 + (j_) * 64 + schunk * 8], &Vs[b3_][wave * 8][0]); \
  } while (0)

  STAGE(0, 0);
  STAGE(1, 1);
  VM("2");   // tile 0 landed; tile 1 in flight
  PH_BAR;

  for (int kb = 0; kb < nkb; ++kb) {
    const int cur = kb % 3;
    const int kbase = kb * 64;
    const bool more = (kb + 2 < nkb);
    if (more) {
      const int j = kb + 2;
      STAGE(j, j % 3);
    }
    if (kbase <= qw + 15) {
      const bf16* kt = ks0 + cur * kdelta;
      f32x4 st[4] = {};
      __builtin_amdgcn_s_setprio(1);
      #pragma unroll
      for (int kf = 0; kf < 4; ++kf)
        #pragma unroll
        for (int kk = 0; kk < 2; ++kk)
          st[kf] = mfma16(*(const bf16x8*)(kt + fo[kf][kk]), qreg[kk], st[kf]);
      __builtin_amdgcn_s_setprio(0);

      float v[16];
      if (kbase + 63 > qw) {
        const int qrel = qw + c - kbase;
        #pragma unroll
        for (int kf = 0; kf < 4; ++kf)
          #pragma unroll
          for (int rr = 0; rr < 4; ++rr)
            v[kf * 4 + rr] = (kf * 16 + 4 * g + rr <= qrel) ? st[kf][rr] : -1e30f;
      } else {
        #pragma unroll
        for (int kf = 0; kf < 4; ++kf)
          #pragma unroll
          for (int rr = 0; rr < 4; ++rr)
            v[kf * 4 + rr] = st[kf][rr];
      }
      float a0 = fmaxf(v[0], v[1]),  a1 = fmaxf(v[2], v[3]);
      float a2 = fmaxf(v[4], v[5]),  a3 = fmaxf(v[6], v[7]);
      float a4 = fmaxf(v[8], v[9]),  a5 = fmaxf(v[10], v[11]);
      float a6 = fmaxf(v[12], v[13]), a7 = fmaxf(v[14], v[15]);
      float b0 = fmaxf(a0, a1), b1 = fmaxf(a2, a3), b2_ = fmaxf(a4, a5), b3 = fmaxf(a6, a7);
      float tm = fmaxf(fmaxf(b0, b1), fmaxf(b2_, b3));
      tm = fmaxf(tm, __shfl_xor(tm, 16));
      tm = fmaxf(tm, __shfl_xor(tm, 32));
      if (__any(tm > m_ + 8.0f)) {
        const float mn = fmaxf(m_, tm);
        const float alpha = __builtin_amdgcn_exp2f(m_ - mn);
        m_ = mn;
        l_ *= alpha;
        #pragma unroll
        for (int df = 0; df < 4; ++df) {
          oacc[df][0] *= alpha; oacc[df][1] *= alpha;
          oacc[df][2] *= alpha; oacc[df][3] *= alpha;
        }
      }
      float ts = 0.0f;
      bf16 p[16];
      #pragma unroll
      for (int i = 0; i < 16; ++i) {
        const float pv = __builtin_amdgcn_exp2f(v[i] - m_);
        ts += pv;
        p[i] = (bf16)pv;
      }
      ts += __shfl_xor(ts, 16);
      ts += __shfl_xor(ts, 32);
      l_ += ts;
      #pragma unroll
      for (int kf = 0; kf < 4; ++kf) {
        bf16x4 pk = {p[kf * 4], p[kf * 4 + 1], p[kf * 4 + 2], p[kf * 4 + 3]};
        *(bf16x4*)pw[kf] = pk;
      }
      bf16x8 pfrag[2];
      pfrag[0] = *(const bf16x8*)pr[0];
      pfrag[1] = *(const bf16x8*)pr[1];
      const bf16* vt = vs0 + cur * kdelta;
      __builtin_amdgcn_s_setprio(1);
      #pragma unroll
      for (int df = 0; df < 4; ++df)
        #pragma unroll
        for (int kk = 0; kk < 2; ++kk)
          oacc[df] = mfma16(*(const bf16x8*)(vt + fo[df][kk]), pfrag[kk], oacc[df]);
      __builtin_amdgcn_s_setprio(0);
    }
    if (more) { VM("2"); } else { VM("0"); }
    PH_BAR;
  }
#undef STAGE

  const int b = bh >> 4, h = bh & 15;
  const float inv = 1.0f / l_;
  const int s = qw + c;
  #pragma unroll
  for (int df = 0; df < 4; ++df) {
    bf16x4 o;
    #pragma unroll
    for (int rr = 0; rr < 4; ++rr) o[rr] = (bf16)(oacc[df][rr] * inv);
    *(bf16x4*)&O[(size_t)(b * 2048 + s) * ldO + h * 64 + df * 16 + 4 * g] = o;
  }
}

// ---------------- host orchestration ----------------
extern "C" void kernel_launch(void* const* d_in, const int* in_sizes, int n_in,
                              void* d_out, int out_size, void* d_ws, size_t ws_size,
                              hipStream_t stream) {
  const float* x     = (const float*)d_in[0];
  const float* W_qkv = (const float*)d_in[2];
  const float* b_qkv = (const float*)d_in[3];
  const float* W_o   = (const float*)d_in[4];
  const float* b_o   = (const float*)d_in[5];
  const float* ln1w  = (const float*)d_in[6];
  const float* ln1b  = (const float*)d_in[7];
  const float* ln2w  = (const float*)d_in[8];
  const float* ln2b  = (const float*)d_in[9];
  const float* W1    = (const float*)d_in[10];
  const float* b1    = (const float*)d_in[11];
  const float* W2    = (const float*)d_in[12];
  const float* b2    = (const float*)d_in[13];
  const float* freqs = (const float*)d_in[14];
  float* out = (float*)d_out;

  char* ws = (char*)d_ws;
  const size_t MB = (size_t)1 << 20;
  bf16* h1   = (bf16*)(ws + 0 * MB);
  bf16* h2   = (bf16*)(ws + 8 * MB);
  bf16* wQKV = (bf16*)(ws + 16 * MB);
  bf16* wCat = (bf16*)(ws + 22 * MB);
  bf16* w1   = (bf16*)(ws + 32 * MB);
  bf16* qkv  = (bf16*)(ws + 40 * MB);
  bf16* Qb   = (bf16*)(ws + 64 * MB);
  bf16* Kb   = (bf16*)(ws + 72 * MB);
  bf16* VTb  = (bf16*)(ws + 80 * MB);
  bf16* A2   = (bf16*)(ws + 88 * MB);
  float* p0  = (float*)(ws + 0 * MB);
  float* p1  = (float*)(ws + 40 * MB);
  float* p2  = (float*)(ws + 64 * MB);

  ln_dual<<<4096, 256, 0, stream>>>(x, ln1w, ln1b, ln2w, ln2b, h1, h2);
  cast_f32_bf16<<<3072, 256, 0, stream>>>(W_qkv, wQKV, 786432);
  cast_f32_bf16<<<4096, 256, 0, stream>>>(W1, w1, 1048576);
  cast_row<<<1024, 256, 0, stream>>>(W_o, wCat, 5120, 1024);
  cast_row<<<1024, 256, 0, stream>>>(W2, wCat + 1024, 5120, 4096);

  gemm256<0><<<192, 512, 0, stream>>>(h1, wQKV, b_qkv, qkv,
                                      nullptr, nullptr, nullptr,
                                      1024, 3072, 192, 12, 16);
  rope_reshape<<<dim3(32, 32), 256, 0, stream>>>(qkv, freqs, Qb, Kb, VTb);
  attn_kernel<<<512, 512, 0, stream>>>(Qb, Kb, VTb, A2, 5120);
  gemm256<1><<<256, 512, 0, stream>>>(h2, w1, b1, A2 + 1024,
                                      nullptr, nullptr, nullptr,
                                      1024, 5120, 256, 16, 16);
  gemm256<2><<<256, 512, 0, stream>>>(A2, wCat, nullptr, p0,
                                      p1, p2, out,
                                      5120, 1024, 64, 4, 20);
  combine_out<<<4096, 256, 0, stream>>>(p0, p1, p2, x, b_o, b2, out);
}

// Round 9
// 209.612 us; speedup vs baseline: 1.2380x; 1.0742x over previous
//
#include <hip/hip_runtime.h>

#define DEV __device__ __forceinline__

typedef __bf16 bf16;
typedef bf16 bf16x4 __attribute__((ext_vector_type(4)));
typedef bf16 bf16x8 __attribute__((ext_vector_type(8)));
typedef float f32x4 __attribute__((ext_vector_type(4)));

DEV f32x4 mfma16(bf16x8 a, bf16x8 b, f32x4 c) {
  return __builtin_amdgcn_mfma_f32_16x16x32_bf16(a, b, c, 0, 0, 0);
}

DEV void gload_lds16(const bf16* g, bf16* l) {
  __builtin_amdgcn_global_load_lds((const __attribute__((address_space(1))) void*)g,
                                   (__attribute__((address_space(3))) void*)l, 16, 0, 0);
}

#define PH_BAR __builtin_amdgcn_s_barrier()
#define VM(NSTR) asm volatile("s_waitcnt vmcnt(" NSTR ")" ::: "memory")
#define WAITBAR(NSTR) asm volatile("s_waitcnt vmcnt(" NSTR ")\n\ts_barrier" ::: "memory")

// tanh-form GELU, exp2+rcp based (~8 VALU ops, overflow-safe both tails).
// gelu(x) = 0.5x(1+tanh(0.79788(x+0.044715x^3))) = x - x/(1+e), e=exp2(x*(2.30199+0.102935x^2))
DEV float fast_gelu(float x) {
  const float z = x * x;
  const float w = __builtin_fmaf(z, 0.1029353f, 2.3019853f);
  const float e = __builtin_amdgcn_exp2f(x * w);
  const float r = __builtin_amdgcn_rcpf(1.0f + e);
  return x - x * r;
}

// ---------------- LayerNorm (both param sets, shared mean/var) ----------------
__global__ __launch_bounds__(256) void ln_dual(
    const float* __restrict__ x,
    const float* __restrict__ w1, const float* __restrict__ b1,
    const float* __restrict__ w2, const float* __restrict__ b2,
    bf16* __restrict__ h1, bf16* __restrict__ h2)
{
  __shared__ float red[2][4];
  const int row = blockIdx.x, t = threadIdx.x;
  const int lane = t & 63, wave = t >> 6;
  const float4 v = ((const float4*)(x + (size_t)row * 1024))[t];
  float vv[4] = {v.x, v.y, v.z, v.w};
  float s = vv[0] + vv[1] + vv[2] + vv[3];
  float q = vv[0]*vv[0] + vv[1]*vv[1] + vv[2]*vv[2] + vv[3]*vv[3];
  #pragma unroll
  for (int o = 32; o; o >>= 1) { s += __shfl_xor(s, o); q += __shfl_xor(q, o); }
  if (lane == 0) { red[0][wave] = s; red[1][wave] = q; }
  __syncthreads();
  s = red[0][0] + red[0][1] + red[0][2] + red[0][3];
  q = red[1][0] + red[1][1] + red[1][2] + red[1][3];
  const float mu = s * (1.0f / 1024.0f);
  const float var = q * (1.0f / 1024.0f) - mu * mu;
  const float rs = rsqrtf(var + 1e-5f);
  bf16x4 o1, o2;
  #pragma unroll
  for (int j = 0; j < 4; ++j) {
    const int i = t * 4 + j;
    const float xh = (vv[j] - mu) * rs;
    o1[j] = (bf16)(xh * w1[i] + b1[i]);
    o2[j] = (bf16)(xh * w2[i] + b2[i]);
  }
  *(bf16x4*)&h1[(size_t)row * 1024 + t * 4] = o1;
  *(bf16x4*)&h2[(size_t)row * 1024 + t * 4] = o2;
}

// ---------------- all weight casts in one dispatch ----------------
// blocks 0..3071: W_qkv -> wQKV (786432 f4, linear)
// blocks 3072..7167: W1 -> w1 (1048576 f4, linear)
// blocks 7168..8191: W_o row r -> wCat[r][0:1024]
// blocks 8192..9215: W2 row r -> wCat[r][1024:5120]
__global__ __launch_bounds__(256) void cast_all(
    const float* __restrict__ Wqkv_f, const float* __restrict__ W1_f,
    const float* __restrict__ Wo_f, const float* __restrict__ W2_f,
    bf16* __restrict__ wQKV, bf16* __restrict__ w1, bf16* __restrict__ wCat)
{
  const int b = blockIdx.x, t = threadIdx.x;
  if (b < 3072) {
    const int i = b * 256 + t;
    const float4 v = ((const float4*)Wqkv_f)[i];
    bf16x4 o = {(bf16)v.x, (bf16)v.y, (bf16)v.z, (bf16)v.w};
    ((bf16x4*)wQKV)[i] = o;
  } else if (b < 7168) {
    const int i = (b - 3072) * 256 + t;
    const float4 v = ((const float4*)W1_f)[i];
    bf16x4 o = {(bf16)v.x, (bf16)v.y, (bf16)v.z, (bf16)v.w};
    ((bf16x4*)w1)[i] = o;
  } else if (b < 8192) {
    const int row = b - 7168;
    const float4 v = *(const float4*)&Wo_f[(size_t)row * 1024 + t * 4];
    bf16x4 o = {(bf16)v.x, (bf16)v.y, (bf16)v.z, (bf16)v.w};
    *(bf16x4*)&wCat[(size_t)row * 5120 + t * 4] = o;
  } else {
    const int row = b - 8192;
    #pragma unroll
    for (int k = 0; k < 4; ++k) {
      const int col = t * 4 + k * 1024;
      const float4 v = *(const float4*)&W2_f[(size_t)row * 4096 + col];
      bf16x4 o = {(bf16)v.x, (bf16)v.y, (bf16)v.z, (bf16)v.w};
      *(bf16x4*)&wCat[(size_t)row * 5120 + 1024 + col] = o;
    }
  }
}

// ---------------- GEMM 256x256xBK64, 8 waves, m201-style 4-phase ----------------
DEV bf16x8 ldfrag(const bf16* unit, int lr, int g) {
  return *(const bf16x8*)&unit[lr * 32 + ((g ^ ((lr >> 1) & 3)) << 3)];
}
DEV void read_bfr(const bf16* unit, int blr, int g, bf16x8 bfr[4]) {
  #pragma unroll
  for (int nj = 0; nj < 4; ++nj) bfr[nj] = ldfrag(unit, blr + nj * 16, g);
}
DEV void read_af(const bf16* unit, int alr, int g, bf16x8 af[4]) {
  #pragma unroll
  for (int ml = 0; ml < 4; ++ml) af[ml] = ldfrag(unit, alr + ml * 16, g);
}
DEV void do_mfma(const bf16x8 af[4], const bf16x8 bfr[4], f32x4 acc[8][4], int mh) {
  __builtin_amdgcn_s_setprio(1);
  #pragma unroll
  for (int ml = 0; ml < 4; ++ml)
    #pragma unroll
    for (int nj = 0; nj < 4; ++nj)
      acc[mh * 4 + ml][nj] = mfma16(af[ml], bfr[nj], acc[mh * 4 + ml][nj]);
  __builtin_amdgcn_s_setprio(0);
}

// EPI: 0 = bf16 + bias; 1 = bf16 gelu(acc+bias); 2 = f32 partial (split-K, no bias)
template <int EPI>
__global__ __launch_bounds__(512) void gemm256(
    const bf16* __restrict__ A, const bf16* __restrict__ B,
    const float* __restrict__ bias, void* __restrict__ Cv,
    float* __restrict__ P1, float* __restrict__ P2, float* __restrict__ P3,
    int K, int ldc, int ntiles, int nbx, int nkt)
{
  __shared__ __align__(16) bf16 As[2][2][2][4096];
  __shared__ __align__(16) bf16 Bs[2][2][2][4096];
  const int tid = threadIdx.x;
  const int lane = tid & 63, wave = tid >> 6;
  const int wm = wave >> 2, wn = wave & 3;
  const int g = lane >> 4, c = lane & 15;
  const int cpx = gridDim.x >> 3;
  const int swz = ((int)blockIdx.x & 7) * cpx + ((int)blockIdx.x >> 3);
  const int tile = swz % ntiles;
  const int sk = swz / ntiles;
  const int bm = (tile / nbx) * 256, bn = (tile % nbx) * 256;

  const int slr = tid >> 2;
  const int sch = (tid & 3) ^ ((tid >> 3) & 3);
  const bf16* aU[2][2];
  const bf16* bU[2][2];
  {
    const bf16* a0 = A + (size_t)(bm + ((slr >> 6) * 128) + (slr & 63)) * K
                       + (size_t)sk * nkt * 64 + sch * 8;
    const bf16* b0 = B + (size_t)(bn + slr) * K + (size_t)sk * nkt * 64 + sch * 8;
    aU[0][0] = a0;            aU[0][1] = a0 + (size_t)64 * K;
    aU[1][0] = a0 + 32;       aU[1][1] = a0 + (size_t)64 * K + 32;
    bU[0][0] = b0;            bU[0][1] = b0 + (size_t)128 * K;
    bU[1][0] = b0 + 32;       bU[1][1] = b0 + (size_t)128 * K + 32;
  }
#define STG_A(bf_, kkh_, ub_, ko_) gload_lds16(aU[kkh_][ub_] + (ko_), &As[bf_][kkh_][ub_][wave * 512])
#define STG_B(bf_, kkh_, ub_, ko_) gload_lds16(bU[kkh_][ub_] + (ko_), &Bs[bf_][kkh_][ub_][wave * 512])

  f32x4 acc[8][4] = {};
  bf16x8 bfr[4], af[4];
  const int alr = (wm << 6) + c;
  const int blr = ((wn & 1) << 6) + c;
  const int bub = wn >> 1;

  STG_B(0, 0, 0, 0); STG_B(0, 0, 1, 0); STG_A(0, 0, 0, 0); STG_A(0, 0, 1, 0);
  STG_B(0, 1, 0, 0); STG_B(0, 1, 1, 0); STG_A(0, 1, 0, 0); STG_A(0, 1, 1, 0);
  WAITBAR("4");

  for (int t = 0; t < nkt - 1; ++t) {
    const int buf = t & 1, nxt = buf ^ 1;
    const int ko = (t + 1) * 64;
    // ---- phase 0: kk=0, mh=0
    read_bfr(&Bs[buf][0][bub][0], blr, g, bfr);
    read_af(&As[buf][0][0][0], alr, g, af);
    STG_B(nxt, 0, 0, ko); STG_B(nxt, 0, 1, ko);
    PH_BAR;
    do_mfma(af, bfr, acc, 0);
    PH_BAR;
    // ---- phase 1: kk=0, mh=1 (bfr reused)
    read_af(&As[buf][0][1][0], alr, g, af);
    STG_A(nxt, 0, 0, ko); STG_A(nxt, 0, 1, ko);
    PH_BAR;
    do_mfma(af, bfr, acc, 1);
    VM("4");
    PH_BAR;
    // ---- phase 2: kk=1, mh=0
    read_bfr(&Bs[buf][1][bub][0], blr, g, bfr);
    read_af(&As[buf][1][0][0], alr, g, af);
    STG_B(nxt, 1, 0, ko); STG_B(nxt, 1, 1, ko);
    PH_BAR;
    do_mfma(af, bfr, acc, 0);
    PH_BAR;
    // ---- phase 3: kk=1, mh=1
    read_af(&As[buf][1][1][0], alr, g, af);
    STG_A(nxt, 1, 0, ko); STG_A(nxt, 1, 1, ko);
    PH_BAR;
    do_mfma(af, bfr, acc, 1);
    VM("4");
    PH_BAR;
  }
  {  // final K-tile: no staging
    const int buf = (nkt - 1) & 1;
    read_bfr(&Bs[buf][0][bub][0], blr, g, bfr);
    read_af(&As[buf][0][0][0], alr, g, af);
    PH_BAR;
    do_mfma(af, bfr, acc, 0);
    PH_BAR;
    read_af(&As[buf][0][1][0], alr, g, af);
    PH_BAR;
    do_mfma(af, bfr, acc, 1);
    VM("0");
    PH_BAR;
    read_bfr(&Bs[buf][1][bub][0], blr, g, bfr);
    read_af(&As[buf][1][0][0], alr, g, af);
    PH_BAR;
    do_mfma(af, bfr, acc, 0);
    PH_BAR;
    read_af(&As[buf][1][1][0], alr, g, af);
    PH_BAR;
    do_mfma(af, bfr, acc, 1);
  }
#undef STG_A
#undef STG_B

  float* Pp = nullptr;
  if constexpr (EPI == 2) Pp = (sk == 1) ? P1 : (sk == 2) ? P2 : (sk == 3) ? P3 : (float*)Cv;
  const int row0 = bm + wm * 128 + 4 * g;
  const int col0 = bn + wn * 64 + c;
  #pragma unroll
  for (int mi = 0; mi < 8; ++mi) {
    #pragma unroll
    for (int nj = 0; nj < 4; ++nj) {
      const int col = col0 + nj * 16;
      float bv = 0.0f;
      if constexpr (EPI < 2) bv = bias[col];
      #pragma unroll
      for (int r = 0; r < 4; ++r) {
        const size_t idx = (size_t)(row0 + mi * 16 + r) * ldc + col;
        float vo = acc[mi][nj][r] + bv;
        if constexpr (EPI == 0) {
          ((bf16*)Cv)[idx] = (bf16)vo;
        } else if constexpr (EPI == 1) {
          ((bf16*)Cv)[idx] = (bf16)fast_gelu(vo);
        } else {
          Pp[idx] = vo;
        }
      }
    }
  }
}

// ---------------- combine: out = p3(=out) + p0 + p1 + p2 + x + b_o + b2 ----------------
__global__ __launch_bounds__(256) void combine_out(
    const float* __restrict__ p0, const float* __restrict__ p1,
    const float* __restrict__ p2, const float* __restrict__ x,
    const float* __restrict__ bo, const float* __restrict__ b2,
    float* __restrict__ out)
{
  const int row = blockIdx.x, t = threadIdx.x;
  const size_t base = (size_t)row * 1024 + t * 4;
  float4 a = *(float4*)&out[base];
  const float4 v0 = *(const float4*)&p0[base];
  const float4 v1 = *(const float4*)&p1[base];
  const float4 v2 = *(const float4*)&p2[base];
  const float4 vx = *(const float4*)&x[base];
  const float4 vb = *(const float4*)&bo[t * 4];
  const float4 vc = *(const float4*)&b2[t * 4];
  a.x += v0.x + v1.x + v2.x + vx.x + vb.x + vc.x;
  a.y += v0.y + v1.y + v2.y + vx.y + vb.y + vc.y;
  a.z += v0.z + v1.z + v2.z + vx.z + vb.z + vc.z;
  a.w += v0.w + v1.w + v2.w + vx.w + vb.w + vc.w;
  *(float4*)&out[base] = a;
}

// ---------------- RoPE + head reshape; also writes V^T ----------------
__global__ __launch_bounds__(256) void rope_reshape(
    const bf16* __restrict__ qkv, const float* __restrict__ freqs,
    bf16* __restrict__ Q, bf16* __restrict__ K, bf16* __restrict__ VT)
{
  __shared__ bf16 vt[64][72];
  const int t = threadIdx.x;
  const int bh = blockIdx.y, b = bh >> 4, h = bh & 15;
  const int sc = blockIdx.x * 64;
  const int sl = t >> 2, s = sc + sl;
  const int d0 = (t & 3) * 16;

  const size_t rowbase = (size_t)(b * 2048 + s) * 3072 + h * 64 + d0;
  const size_t obase = ((size_t)bh * 2048 + s) * 64 + d0;

  #pragma unroll
  for (int which = 0; which < 2; ++which) {
    const bf16* src = qkv + rowbase + which * 1024;
    bf16x8 v0 = *(const bf16x8*)src;
    bf16x8 v1 = *(const bf16x8*)(src + 8);
    if (d0 == 0) {
      bf16x8 r0, r1;
      #pragma unroll
      for (int j = 0; j < 8; ++j) {
        const float cs = freqs[s * 16 + j * 2];
        const float sn = freqs[s * 16 + j * 2 + 1];
        const float x1 = (float)v0[j], x2 = (float)v1[j];
        r0[j] = (bf16)(x1 * cs - x2 * sn);
        r1[j] = (bf16)(x1 * sn + x2 * cs);
      }
      v0 = r0; v1 = r1;
    }
    bf16* dst = (which == 0 ? Q : K) + obase;
    *(bf16x8*)dst = v0;
    *(bf16x8*)(dst + 8) = v1;
  }
  {
    const bf16* src = qkv + rowbase + 2048;
    bf16x8 v0 = *(const bf16x8*)src;
    bf16x8 v1 = *(const bf16x8*)(src + 8);
    #pragma unroll
    for (int j = 0; j < 8; ++j) { vt[sl][d0 + j] = v0[j]; vt[sl][d0 + 8 + j] = v1[j]; }
  }
  __syncthreads();
  {
    const int d = t >> 2;
    const int s0 = (t & 3) * 16;
    bf16x8 o0, o1;
    #pragma unroll
    for (int j = 0; j < 8; ++j) { o0[j] = vt[s0 + j][d]; o1[j] = vt[s0 + 8 + j][d]; }
    bf16* dst = VT + ((size_t)bh * 64 + d) * 2048 + sc + s0;
    *(bf16x8*)dst = o0;
    *(bf16x8*)(dst + 8) = o1;
  }
}

// ---------------- Causal flash attention (v4) ----------------
__global__ __launch_bounds__(512) void attn_kernel(
    const bf16* __restrict__ Q, const bf16* __restrict__ Kg,
    const bf16* __restrict__ VTg, bf16* __restrict__ O, int ldO)
{
  __shared__ __align__(16) bf16 Ks[3][64][64];
  __shared__ __align__(16) bf16 Vs[3][64][64];
  __shared__ __align__(16) bf16 Ps[8][16][64];

  const int tid = threadIdx.x;
  const int lane = tid & 63, wave = tid >> 6;
  const int g = lane >> 4, c = lane & 15;
  const int L = blockIdx.x;
  const int half = L >> 8, r = L & 255;
  const int bh = (half << 4) | (r >> 4);
  const int qtile = half ? (15 - (r & 15)) : (r & 15);
  const int qw = qtile * 128 + wave * 16;

  const bf16* Qp = Q + (size_t)bh * 2048 * 64;
  const bf16* Kp = Kg + (size_t)bh * 2048 * 64;
  const bf16* Vp = VTg + (size_t)bh * 64 * 2048;

  const int srow = lane >> 3;
  const int schunk = (lane & 7) ^ srow;
  const int svr = wave * 8 + srow;
  const size_t kdelta = (size_t)64 * 64;

  bf16x8 qreg[2];
  {
    const float qs = 0.125f * 1.44269504f;
    bf16x8 t0 = *(const bf16x8*)&Qp[(size_t)(qw + c) * 64 + g * 8];
    bf16x8 t1 = *(const bf16x8*)&Qp[(size_t)(qw + c) * 64 + 32 + g * 8];
    #pragma unroll
    for (int j = 0; j < 8; ++j) {
      qreg[0][j] = (bf16)((float)t0[j] * qs);
      qreg[1][j] = (bf16)((float)t1[j] * qs);
    }
  }

  const int cq = c & 7;
  int fo[4][2];
  #pragma unroll
  for (int i = 0; i < 4; ++i)
    #pragma unroll
    for (int kk = 0; kk < 2; ++kk)
      fo[i][kk] = (i * 16 + c) * 64 + (((kk * 4 + g) ^ cq) << 3);
  bf16* pw[4];
  #pragma unroll
  for (int kf = 0; kf < 4; ++kf)
    pw[kf] = &Ps[wave][c][((((kf * 2 + (g >> 1)) ^ cq) << 3)) + ((g & 1) << 2)];
  const bf16* pr[2];
  #pragma unroll
  for (int kk = 0; kk < 2; ++kk)
    pr[kk] = &Ps[wave][c][((kk * 4 + g) ^ cq) << 3];
  const bf16* ks0 = &Ks[0][0][0];
  const bf16* vs0 = &Vs[0][0][0];

  f32x4 oacc[4] = {};
  float m_ = -1e30f, l_ = 0.0f;

  const int nkb = 2 * qtile + 2;
#define STAGE(j_, b3_) do {                                                        \
    gload_lds16(&Kp[(size_t)((j_) * 64 + svr) * 64 + schunk * 8], &Ks[b3_][wave * 8][0]); \
    gload_lds16(&Vp[(size_t)svr * 2048 + (j_) * 64 + schunk * 8], &Vs[b3_][wave * 8][0]); \
  } while (0)

  STAGE(0, 0);
  STAGE(1, 1);
  VM("2");
  PH_BAR;

  for (int kb = 0; kb < nkb; ++kb) {
    const int cur = kb % 3;
    const int kbase = kb * 64;
    const bool more = (kb + 2 < nkb);
    if (more) {
      const int j = kb + 2;
      STAGE(j, j % 3);
    }
    if (kbase <= qw + 15) {
      const bf16* kt = ks0 + cur * kdelta;
      f32x4 st[4] = {};
      __builtin_amdgcn_s_setprio(1);
      #pragma unroll
      for (int kf = 0; kf < 4; ++kf)
        #pragma unroll
        for (int kk = 0; kk < 2; ++kk)
          st[kf] = mfma16(*(const bf16x8*)(kt + fo[kf][kk]), qreg[kk], st[kf]);
      __builtin_amdgcn_s_setprio(0);

      float v[16];
      if (kbase + 63 > qw) {
        const int qrel = qw + c - kbase;
        #pragma unroll
        for (int kf = 0; kf < 4; ++kf)
          #pragma unroll
          for (int rr = 0; rr < 4; ++rr)
            v[kf * 4 + rr] = (kf * 16 + 4 * g + rr <= qrel) ? st[kf][rr] : -1e30f;
      } else {
        #pragma unroll
        for (int kf = 0; kf < 4; ++kf)
          #pragma unroll
          for (int rr = 0; rr < 4; ++rr)
            v[kf * 4 + rr] = st[kf][rr];
      }
      float a0 = fmaxf(v[0], v[1]),  a1 = fmaxf(v[2], v[3]);
      float a2 = fmaxf(v[4], v[5]),  a3 = fmaxf(v[6], v[7]);
      float a4 = fmaxf(v[8], v[9]),  a5 = fmaxf(v[10], v[11]);
      float a6 = fmaxf(v[12], v[13]), a7 = fmaxf(v[14], v[15]);
      float b0 = fmaxf(a0, a1), b1 = fmaxf(a2, a3), b2_ = fmaxf(a4, a5), b3 = fmaxf(a6, a7);
      float tm = fmaxf(fmaxf(b0, b1), fmaxf(b2_, b3));
      tm = fmaxf(tm, __shfl_xor(tm, 16));
      tm = fmaxf(tm, __shfl_xor(tm, 32));
      if (__any(tm > m_ + 8.0f)) {
        const float mn = fmaxf(m_, tm);
        const float alpha = __builtin_amdgcn_exp2f(m_ - mn);
        m_ = mn;
        l_ *= alpha;
        #pragma unroll
        for (int df = 0; df < 4; ++df) {
          oacc[df][0] *= alpha; oacc[df][1] *= alpha;
          oacc[df][2] *= alpha; oacc[df][3] *= alpha;
        }
      }
      float ts = 0.0f;
      bf16 p[16];
      #pragma unroll
      for (int i = 0; i < 16; ++i) {
        const float pv = __builtin_amdgcn_exp2f(v[i] - m_);
        ts += pv;
        p[i] = (bf16)pv;
      }
      ts += __shfl_xor(ts, 16);
      ts += __shfl_xor(ts, 32);
      l_ += ts;
      #pragma unroll
      for (int kf = 0; kf < 4; ++kf) {
        bf16x4 pk = {p[kf * 4], p[kf * 4 + 1], p[kf * 4 + 2], p[kf * 4 + 3]};
        *(bf16x4*)pw[kf] = pk;
      }
      bf16x8 pfrag[2];
      pfrag[0] = *(const bf16x8*)pr[0];
      pfrag[1] = *(const bf16x8*)pr[1];
      const bf16* vt = vs0 + cur * kdelta;
      __builtin_amdgcn_s_setprio(1);
      #pragma unroll
      for (int df = 0; df < 4; ++df)
        #pragma unroll
        for (int kk = 0; kk < 2; ++kk)
          oacc[df] = mfma16(*(const bf16x8*)(vt + fo[df][kk]), pfrag[kk], oacc[df]);
      __builtin_amdgcn_s_setprio(0);
    }
    if (more) { VM("2"); } else { VM("0"); }
    PH_BAR;
  }
#undef STAGE

  const int b = bh >> 4, h = bh & 15;
  const float inv = 1.0f / l_;
  const int s = qw + c;
  #pragma unroll
  for (int df = 0; df < 4; ++df) {
    bf16x4 o;
    #pragma unroll
    for (int rr = 0; rr < 4; ++rr) o[rr] = (bf16)(oacc[df][rr] * inv);
    *(bf16x4*)&O[(size_t)(b * 2048 + s) * ldO + h * 64 + df * 16 + 4 * g] = o;
  }
}

// ---------------- host orchestration ----------------
extern "C" void kernel_launch(void* const* d_in, const int* in_sizes, int n_in,
                              void* d_out, int out_size, void* d_ws, size_t ws_size,
                              hipStream_t stream) {
  const float* x     = (const float*)d_in[0];
  const float* W_qkv = (const float*)d_in[2];
  const float* b_qkv = (const float*)d_in[3];
  const float* W_o   = (const float*)d_in[4];
  const float* b_o   = (const float*)d_in[5];
  const float* ln1w  = (const float*)d_in[6];
  const float* ln1b  = (const float*)d_in[7];
  const float* ln2w  = (const float*)d_in[8];
  const float* ln2b  = (const float*)d_in[9];
  const float* W1    = (const float*)d_in[10];
  const float* b1    = (const float*)d_in[11];
  const float* W2    = (const float*)d_in[12];
  const float* b2    = (const float*)d_in[13];
  const float* freqs = (const float*)d_in[14];
  float* out = (float*)d_out;

  char* ws = (char*)d_ws;
  const size_t MB = (size_t)1 << 20;
  bf16* h1   = (bf16*)(ws + 0 * MB);
  bf16* h2   = (bf16*)(ws + 8 * MB);
  bf16* wQKV = (bf16*)(ws + 16 * MB);
  bf16* wCat = (bf16*)(ws + 22 * MB);
  bf16* w1   = (bf16*)(ws + 32 * MB);
  bf16* qkv  = (bf16*)(ws + 40 * MB);
  bf16* Qb   = (bf16*)(ws + 64 * MB);
  bf16* Kb   = (bf16*)(ws + 72 * MB);
  bf16* VTb  = (bf16*)(ws + 80 * MB);
  bf16* A2   = (bf16*)(ws + 88 * MB);
  float* p0  = (float*)(ws + 0 * MB);
  float* p1  = (float*)(ws + 40 * MB);
  float* p2  = (float*)(ws + 64 * MB);

  ln_dual<<<4096, 256, 0, stream>>>(x, ln1w, ln1b, ln2w, ln2b, h1, h2);
  cast_all<<<9216, 256, 0, stream>>>(W_qkv, W1, W_o, W2, wQKV, w1, wCat);

  gemm256<0><<<192, 512, 0, stream>>>(h1, wQKV, b_qkv, qkv,
                                      nullptr, nullptr, nullptr,
                                      1024, 3072, 192, 12, 16);
  rope_reshape<<<dim3(32, 32), 256, 0, stream>>>(qkv, freqs, Qb, Kb, VTb);
  attn_kernel<<<512, 512, 0, stream>>>(Qb, Kb, VTb, A2, 5120);
  gemm256<1><<<256, 512, 0, stream>>>(h2, w1, b1, A2 + 1024,
                                      nullptr, nullptr, nullptr,
                                      1024, 5120, 256, 16, 16);
  gemm256<2><<<256, 512, 0, stream>>>(A2, wCat, nullptr, p0,
                                      p1, p2, out,
                                      5120, 1024, 64, 4, 20);
  combine_out<<<4096, 256, 0, stream>>>(p0, p1, p2, x, b_o, b2, out);
}

// Round 10
// 205.982 us; speedup vs baseline: 1.2598x; 1.0176x over previous
//
#include <hip/hip_runtime.h>

#define DEV __device__ __forceinline__

typedef __bf16 bf16;
typedef bf16 bf16x4 __attribute__((ext_vector_type(4)));
typedef bf16 bf16x8 __attribute__((ext_vector_type(8)));
typedef float f32x4 __attribute__((ext_vector_type(4)));

DEV f32x4 mfma16(bf16x8 a, bf16x8 b, f32x4 c) {
  return __builtin_amdgcn_mfma_f32_16x16x32_bf16(a, b, c, 0, 0, 0);
}

DEV void gload_lds16(const bf16* g, bf16* l) {
  __builtin_amdgcn_global_load_lds((const __attribute__((address_space(1))) void*)g,
                                   (__attribute__((address_space(3))) void*)l, 16, 0, 0);
}

#define PH_BAR __builtin_amdgcn_s_barrier()
#define VM(NSTR) asm volatile("s_waitcnt vmcnt(" NSTR ")" ::: "memory")
#define WAITBAR(NSTR) asm volatile("s_waitcnt vmcnt(" NSTR ")\n\ts_barrier" ::: "memory")

// tanh-form GELU, exp2+rcp based (~8 VALU ops, overflow-safe both tails).
DEV float fast_gelu(float x) {
  const float z = x * x;
  const float w = __builtin_fmaf(z, 0.1029353f, 2.3019853f);
  const float e = __builtin_amdgcn_exp2f(x * w);
  const float r = __builtin_amdgcn_rcpf(1.0f + e);
  return x - x * r;
}

// ---------------- LayerNorm (both param sets, shared mean/var) ----------------
__global__ __launch_bounds__(256) void ln_dual(
    const float* __restrict__ x,
    const float* __restrict__ w1, const float* __restrict__ b1,
    const float* __restrict__ w2, const float* __restrict__ b2,
    bf16* __restrict__ h1, bf16* __restrict__ h2)
{
  __shared__ float red[2][4];
  const int row = blockIdx.x, t = threadIdx.x;
  const int lane = t & 63, wave = t >> 6;
  const float4 v = ((const float4*)(x + (size_t)row * 1024))[t];
  float vv[4] = {v.x, v.y, v.z, v.w};
  float s = vv[0] + vv[1] + vv[2] + vv[3];
  float q = vv[0]*vv[0] + vv[1]*vv[1] + vv[2]*vv[2] + vv[3]*vv[3];
  #pragma unroll
  for (int o = 32; o; o >>= 1) { s += __shfl_xor(s, o); q += __shfl_xor(q, o); }
  if (lane == 0) { red[0][wave] = s; red[1][wave] = q; }
  __syncthreads();
  s = red[0][0] + red[0][1] + red[0][2] + red[0][3];
  q = red[1][0] + red[1][1] + red[1][2] + red[1][3];
  const float mu = s * (1.0f / 1024.0f);
  const float var = q * (1.0f / 1024.0f) - mu * mu;
  const float rs = rsqrtf(var + 1e-5f);
  bf16x4 o1, o2;
  #pragma unroll
  for (int j = 0; j < 4; ++j) {
    const int i = t * 4 + j;
    const float xh = (vv[j] - mu) * rs;
    o1[j] = (bf16)(xh * w1[i] + b1[i]);
    o2[j] = (bf16)(xh * w2[i] + b2[i]);
  }
  *(bf16x4*)&h1[(size_t)row * 1024 + t * 4] = o1;
  *(bf16x4*)&h2[(size_t)row * 1024 + t * 4] = o2;
}

// ---------------- all weight casts in one dispatch ----------------
__global__ __launch_bounds__(256) void cast_all(
    const float* __restrict__ Wqkv_f, const float* __restrict__ W1_f,
    const float* __restrict__ Wo_f, const float* __restrict__ W2_f,
    bf16* __restrict__ wQKV, bf16* __restrict__ w1, bf16* __restrict__ wCat)
{
  const int b = blockIdx.x, t = threadIdx.x;
  if (b < 3072) {
    const int i = b * 256 + t;
    const float4 v = ((const float4*)Wqkv_f)[i];
    bf16x4 o = {(bf16)v.x, (bf16)v.y, (bf16)v.z, (bf16)v.w};
    ((bf16x4*)wQKV)[i] = o;
  } else if (b < 7168) {
    const int i = (b - 3072) * 256 + t;
    const float4 v = ((const float4*)W1_f)[i];
    bf16x4 o = {(bf16)v.x, (bf16)v.y, (bf16)v.z, (bf16)v.w};
    ((bf16x4*)w1)[i] = o;
  } else if (b < 8192) {
    const int row = b - 7168;
    const float4 v = *(const float4*)&Wo_f[(size_t)row * 1024 + t * 4];
    bf16x4 o = {(bf16)v.x, (bf16)v.y, (bf16)v.z, (bf16)v.w};
    *(bf16x4*)&wCat[(size_t)row * 5120 + t * 4] = o;
  } else {
    const int row = b - 8192;
    #pragma unroll
    for (int k = 0; k < 4; ++k) {
      const int col = t * 4 + k * 1024;
      const float4 v = *(const float4*)&W2_f[(size_t)row * 4096 + col];
      bf16x4 o = {(bf16)v.x, (bf16)v.y, (bf16)v.z, (bf16)v.w};
      *(bf16x4*)&wCat[(size_t)row * 5120 + 1024 + col] = o;
    }
  }
}

// ---------------- GEMM 256x256xBK64, 8 waves, m201-style 4-phase ----------------
DEV bf16x8 ldfrag(const bf16* unit, int lr, int g) {
  return *(const bf16x8*)&unit[lr * 32 + ((g ^ ((lr >> 1) & 3)) << 3)];
}
DEV void read_bfr(const bf16* unit, int blr, int g, bf16x8 bfr[4]) {
  #pragma unroll
  for (int nj = 0; nj < 4; ++nj) bfr[nj] = ldfrag(unit, blr + nj * 16, g);
}
DEV void read_af(const bf16* unit, int alr, int g, bf16x8 af[4]) {
  #pragma unroll
  for (int ml = 0; ml < 4; ++ml) af[ml] = ldfrag(unit, alr + ml * 16, g);
}
DEV void do_mfma(const bf16x8 af[4], const bf16x8 bfr[4], f32x4 acc[8][4], int mh) {
  __builtin_amdgcn_s_setprio(1);
  #pragma unroll
  for (int ml = 0; ml < 4; ++ml)
    #pragma unroll
    for (int nj = 0; nj < 4; ++nj)
      acc[mh * 4 + ml][nj] = mfma16(af[ml], bfr[nj], acc[mh * 4 + ml][nj]);
  __builtin_amdgcn_s_setprio(0);
}

// EPI: 0 = bf16 + bias; 1 = bf16 gelu(acc+bias); 2 = f32 partial (split-K, no bias)
template <int EPI>
__global__ __launch_bounds__(512) void gemm256(
    const bf16* __restrict__ A, const bf16* __restrict__ B,
    const float* __restrict__ bias, void* __restrict__ Cv,
    float* __restrict__ P1, float* __restrict__ P2, float* __restrict__ P3,
    int K, int ldc, int ntiles, int nbx, int nkt)
{
  __shared__ __align__(16) bf16 As[2][2][2][4096];
  __shared__ __align__(16) bf16 Bs[2][2][2][4096];
  const int tid = threadIdx.x;
  const int lane = tid & 63, wave = tid >> 6;
  const int wm = wave >> 2, wn = wave & 3;
  const int g = lane >> 4, c = lane & 15;
  const int cpx = gridDim.x >> 3;
  const int swz = ((int)blockIdx.x & 7) * cpx + ((int)blockIdx.x >> 3);
  const int tile = swz % ntiles;
  const int sk = swz / ntiles;
  const int bm = (tile / nbx) * 256, bn = (tile % nbx) * 256;

  const int slr = tid >> 2;
  const int sch = (tid & 3) ^ ((tid >> 3) & 3);
  const bf16* aU[2][2];
  const bf16* bU[2][2];
  {
    const bf16* a0 = A + (size_t)(bm + ((slr >> 6) * 128) + (slr & 63)) * K
                       + (size_t)sk * nkt * 64 + sch * 8;
    const bf16* b0 = B + (size_t)(bn + slr) * K + (size_t)sk * nkt * 64 + sch * 8;
    aU[0][0] = a0;            aU[0][1] = a0 + (size_t)64 * K;
    aU[1][0] = a0 + 32;       aU[1][1] = a0 + (size_t)64 * K + 32;
    bU[0][0] = b0;            bU[0][1] = b0 + (size_t)128 * K;
    bU[1][0] = b0 + 32;       bU[1][1] = b0 + (size_t)128 * K + 32;
  }
#define STG_A(bf_, kkh_, ub_, ko_) gload_lds16(aU[kkh_][ub_] + (ko_), &As[bf_][kkh_][ub_][wave * 512])
#define STG_B(bf_, kkh_, ub_, ko_) gload_lds16(bU[kkh_][ub_] + (ko_), &Bs[bf_][kkh_][ub_][wave * 512])

  f32x4 acc[8][4] = {};
  bf16x8 bfr[4], af[4];
  const int alr = (wm << 6) + c;
  const int blr = ((wn & 1) << 6) + c;
  const int bub = wn >> 1;

  STG_B(0, 0, 0, 0); STG_B(0, 0, 1, 0); STG_A(0, 0, 0, 0); STG_A(0, 0, 1, 0);
  STG_B(0, 1, 0, 0); STG_B(0, 1, 1, 0); STG_A(0, 1, 0, 0); STG_A(0, 1, 1, 0);
  WAITBAR("4");

  for (int t = 0; t < nkt - 1; ++t) {
    const int buf = t & 1, nxt = buf ^ 1;
    const int ko = (t + 1) * 64;
    // ---- phase 0: kk=0, mh=0
    read_bfr(&Bs[buf][0][bub][0], blr, g, bfr);
    read_af(&As[buf][0][0][0], alr, g, af);
    STG_B(nxt, 0, 0, ko); STG_B(nxt, 0, 1, ko);
    PH_BAR;
    do_mfma(af, bfr, acc, 0);
    PH_BAR;
    // ---- phase 1: kk=0, mh=1 (bfr reused)
    read_af(&As[buf][0][1][0], alr, g, af);
    STG_A(nxt, 0, 0, ko); STG_A(nxt, 0, 1, ko);
    PH_BAR;
    do_mfma(af, bfr, acc, 1);
    VM("4");
    PH_BAR;
    // ---- phase 2: kk=1, mh=0
    read_bfr(&Bs[buf][1][bub][0], blr, g, bfr);
    read_af(&As[buf][1][0][0], alr, g, af);
    STG_B(nxt, 1, 0, ko); STG_B(nxt, 1, 1, ko);
    PH_BAR;
    do_mfma(af, bfr, acc, 0);
    PH_BAR;
    // ---- phase 3: kk=1, mh=1
    read_af(&As[buf][1][1][0], alr, g, af);
    STG_A(nxt, 1, 0, ko); STG_A(nxt, 1, 1, ko);
    PH_BAR;
    do_mfma(af, bfr, acc, 1);
    VM("4");
    PH_BAR;
  }
  {  // final K-tile: no staging
    const int buf = (nkt - 1) & 1;
    read_bfr(&Bs[buf][0][bub][0], blr, g, bfr);
    read_af(&As[buf][0][0][0], alr, g, af);
    PH_BAR;
    do_mfma(af, bfr, acc, 0);
    PH_BAR;
    read_af(&As[buf][0][1][0], alr, g, af);
    PH_BAR;
    do_mfma(af, bfr, acc, 1);
    VM("0");
    PH_BAR;
    read_bfr(&Bs[buf][1][bub][0], blr, g, bfr);
    read_af(&As[buf][1][0][0], alr, g, af);
    PH_BAR;
    do_mfma(af, bfr, acc, 0);
    PH_BAR;
    read_af(&As[buf][1][1][0], alr, g, af);
    PH_BAR;
    do_mfma(af, bfr, acc, 1);
  }
#undef STG_A
#undef STG_B

  float* Pp = nullptr;
  if constexpr (EPI == 2) Pp = (sk == 1) ? P1 : (sk == 2) ? P2 : (sk == 3) ? P3 : (float*)Cv;
  const int row0 = bm + wm * 128 + 4 * g;
  const int col0 = bn + wn * 64 + c;
  #pragma unroll
  for (int mi = 0; mi < 8; ++mi) {
    #pragma unroll
    for (int nj = 0; nj < 4; ++nj) {
      const int col = col0 + nj * 16;
      float bv = 0.0f;
      if constexpr (EPI < 2) bv = bias[col];
      #pragma unroll
      for (int r = 0; r < 4; ++r) {
        const size_t idx = (size_t)(row0 + mi * 16 + r) * ldc + col;
        float vo = acc[mi][nj][r] + bv;
        if constexpr (EPI == 0) {
          ((bf16*)Cv)[idx] = (bf16)vo;
        } else if constexpr (EPI == 1) {
          ((bf16*)Cv)[idx] = (bf16)fast_gelu(vo);
        } else {
          Pp[idx] = vo;
        }
      }
    }
  }
}

// ---------------- combine: out = p3(=out) + p0 + p1 + p2 + x + b_o + b2 ----------------
__global__ __launch_bounds__(256) void combine_out(
    const float* __restrict__ p0, const float* __restrict__ p1,
    const float* __restrict__ p2, const float* __restrict__ x,
    const float* __restrict__ bo, const float* __restrict__ b2,
    float* __restrict__ out)
{
  const int row = blockIdx.x, t = threadIdx.x;
  const size_t base = (size_t)row * 1024 + t * 4;
  float4 a = *(float4*)&out[base];
  const float4 v0 = *(const float4*)&p0[base];
  const float4 v1 = *(const float4*)&p1[base];
  const float4 v2 = *(const float4*)&p2[base];
  const float4 vx = *(const float4*)&x[base];
  const float4 vb = *(const float4*)&bo[t * 4];
  const float4 vc = *(const float4*)&b2[t * 4];
  a.x += v0.x + v1.x + v2.x + vx.x + vb.x + vc.x;
  a.y += v0.y + v1.y + v2.y + vx.y + vb.y + vc.y;
  a.z += v0.z + v1.z + v2.z + vx.z + vb.z + vc.z;
  a.w += v0.w + v1.w + v2.w + vx.w + vb.w + vc.w;
  *(float4*)&out[base] = a;
}

// ---------------- RoPE + head reshape; also writes V^T ----------------
__global__ __launch_bounds__(256) void rope_reshape(
    const bf16* __restrict__ qkv, const float* __restrict__ freqs,
    bf16* __restrict__ Q, bf16* __restrict__ K, bf16* __restrict__ VT)
{
  __shared__ bf16 vt[64][72];
  const int t = threadIdx.x;
  const int bh = blockIdx.y, b = bh >> 4, h = bh & 15;
  const int sc = blockIdx.x * 64;
  const int sl = t >> 2, s = sc + sl;
  const int d0 = (t & 3) * 16;

  const size_t rowbase = (size_t)(b * 2048 + s) * 3072 + h * 64 + d0;
  const size_t obase = ((size_t)bh * 2048 + s) * 64 + d0;

  #pragma unroll
  for (int which = 0; which < 2; ++which) {
    const bf16* src = qkv + rowbase + which * 1024;
    bf16x8 v0 = *(const bf16x8*)src;
    bf16x8 v1 = *(const bf16x8*)(src + 8);
    if (d0 == 0) {
      bf16x8 r0, r1;
      #pragma unroll
      for (int j = 0; j < 8; ++j) {
        const float cs = freqs[s * 16 + j * 2];
        const float sn = freqs[s * 16 + j * 2 + 1];
        const float x1 = (float)v0[j], x2 = (float)v1[j];
        r0[j] = (bf16)(x1 * cs - x2 * sn);
        r1[j] = (bf16)(x1 * sn + x2 * cs);
      }
      v0 = r0; v1 = r1;
    }
    bf16* dst = (which == 0 ? Q : K) + obase;
    *(bf16x8*)dst = v0;
    *(bf16x8*)(dst + 8) = v1;
  }
  {
    const bf16* src = qkv + rowbase + 2048;
    bf16x8 v0 = *(const bf16x8*)src;
    bf16x8 v1 = *(const bf16x8*)(src + 8);
    #pragma unroll
    for (int j = 0; j < 8; ++j) { vt[sl][d0 + j] = v0[j]; vt[sl][d0 + 8 + j] = v1[j]; }
  }
  __syncthreads();
  {
    const int d = t >> 2;
    const int s0 = (t & 3) * 16;
    bf16x8 o0, o1;
    #pragma unroll
    for (int j = 0; j < 8; ++j) { o0[j] = vt[s0 + j][d]; o1[j] = vt[s0 + 8 + j][d]; }
    bf16* dst = VT + ((size_t)bh * 64 + d) * 2048 + sc + s0;
    *(bf16x8*)dst = o0;
    *(bf16x8*)(dst + 8) = o1;
  }
}

// ---------------- Causal flash attention (v5) ----------------
// R10: T15-lite software pipeline on the 3-buffer scheme — per body:
//   STAGE(j+2) ; QKT(j+1)->stNext ; SM(j)+PV(j) from stCur ; vmcnt(0) ; barrier.
// QKT(j+1)'s MFMAs execute in the matrix pipe while SM(j)'s VALU runs (SM
// depends only on last body's st). Two score reg sets (stA/stB), 2-body unroll
// so all indices are compile-time (rule #20). Row-sum via mfma(ones,P) — kills
// 16 VALU adds + 2 DS shfls; cross-lane max shfls only inside the rare
// rescale branch (__any on lane-local max triggers).
__global__ __launch_bounds__(512, 4) void attn_kernel(
    const bf16* __restrict__ Q, const bf16* __restrict__ Kg,
    const bf16* __restrict__ VTg, bf16* __restrict__ O, int ldO)
{
  __shared__ __align__(16) bf16 Ks[3][64][64];
  __shared__ __align__(16) bf16 Vs[3][64][64];
  __shared__ __align__(16) bf16 Ps[8][16][64];

  const int tid = threadIdx.x;
  const int lane = tid & 63, wave = tid >> 6;
  const int g = lane >> 4, c = lane & 15;
  const int L = blockIdx.x;
  const int half = L >> 8, r = L & 255;
  const int bh = (half << 4) | (r >> 4);
  const int qtile = half ? (15 - (r & 15)) : (r & 15);
  const int qw = qtile * 128 + wave * 16;

  const bf16* Qp = Q + (size_t)bh * 2048 * 64;
  const bf16* Kp = Kg + (size_t)bh * 2048 * 64;
  const bf16* Vp = VTg + (size_t)bh * 64 * 2048;

  const int srow = lane >> 3;
  const int schunk = (lane & 7) ^ srow;
  const int svr = wave * 8 + srow;
  const size_t kdelta = (size_t)64 * 64;

  bf16x8 qreg[2];
  {
    const float qs = 0.125f * 1.44269504f;
    bf16x8 t0 = *(const bf16x8*)&Qp[(size_t)(qw + c) * 64 + g * 8];
    bf16x8 t1 = *(const bf16x8*)&Qp[(size_t)(qw + c) * 64 + 32 + g * 8];
    #pragma unroll
    for (int j = 0; j < 8; ++j) {
      qreg[0][j] = (bf16)((float)t0[j] * qs);
      qreg[1][j] = (bf16)((float)t1[j] * qs);
    }
  }
  bf16x8 ones;
  #pragma unroll
  for (int j = 0; j < 8; ++j) ones[j] = (bf16)1.0f;

  const int cq = c & 7;
  int fo[4][2];
  #pragma unroll
  for (int i = 0; i < 4; ++i)
    #pragma unroll
    for (int kk = 0; kk < 2; ++kk)
      fo[i][kk] = (i * 16 + c) * 64 + (((kk * 4 + g) ^ cq) << 3);
  bf16* pw[4];
  #pragma unroll
  for (int kf = 0; kf < 4; ++kf)
    pw[kf] = &Ps[wave][c][((((kf * 2 + (g >> 1)) ^ cq) << 3)) + ((g & 1) << 2)];
  const bf16* pr[2];
  #pragma unroll
  for (int kk = 0; kk < 2; ++kk)
    pr[kk] = &Ps[wave][c][((kk * 4 + g) ^ cq) << 3];
  const bf16* ks0 = &Ks[0][0][0];
  const bf16* vs0 = &Vs[0][0][0];

  f32x4 oacc[4] = {};
  f32x4 lacc = {};
  float m_ = -1e30f;

  const int nkb = 2 * qtile + 2;  // even, >= 2
#define STAGE(j_, b3_) do {                                                        \
    gload_lds16(&Kp[(size_t)((j_) * 64 + svr) * 64 + schunk * 8], &Ks[b3_][wave * 8][0]); \
    gload_lds16(&Vp[(size_t)svr * 2048 + (j_) * 64 + schunk * 8], &Vs[b3_][wave * 8][0]); \
  } while (0)

  // QK^T for tile at buffer bufi -> st
  auto qkt = [&](f32x4* st, int bufi) {
    const bf16* kt = ks0 + bufi * kdelta;
    __builtin_amdgcn_s_setprio(1);
    #pragma unroll
    for (int kf = 0; kf < 4; ++kf) {
      f32x4 z = {};
      z = mfma16(*(const bf16x8*)(kt + fo[kf][0]), qreg[0], z);
      st[kf] = mfma16(*(const bf16x8*)(kt + fo[kf][1]), qreg[1], z);
    }
    __builtin_amdgcn_s_setprio(0);
  };

  // softmax + PV for tile j using st (scores from a prior qkt)
  auto smpv = [&](const f32x4* st, int j_, int bufi) {
    const int kbase = j_ * 64;
    float v[16];
    if (kbase + 63 > qw) {
      const int qrel = qw + c - kbase;
      #pragma unroll
      for (int kf = 0; kf < 4; ++kf)
        #pragma unroll
        for (int rr = 0; rr < 4; ++rr)
          v[kf * 4 + rr] = (kf * 16 + 4 * g + rr <= qrel) ? st[kf][rr] : -1e30f;
    } else {
      #pragma unroll
      for (int kf = 0; kf < 4; ++kf)
        #pragma unroll
        for (int rr = 0; rr < 4; ++rr)
          v[kf * 4 + rr] = st[kf][rr];
    }
    // lane-local max (max3-fusable tree)
    float u0 = fmaxf(fmaxf(v[0], v[1]), v[2]);
    float u1 = fmaxf(fmaxf(v[3], v[4]), v[5]);
    float u2 = fmaxf(fmaxf(v[6], v[7]), v[8]);
    float u3 = fmaxf(fmaxf(v[9], v[10]), v[11]);
    float u4 = fmaxf(fmaxf(v[12], v[13]), v[14]);
    float tm = fmaxf(fmaxf(fmaxf(u0, u1), u2), fmaxf(fmaxf(u3, u4), v[15]));
    // defer-max: rescale only when some lane's max grew past m_+8; row-max
    // shfls live inside the branch.
    if (__any(tm > m_ + 8.0f)) {
      float tr = fmaxf(tm, __shfl_xor(tm, 16));
      tr = fmaxf(tr, __shfl_xor(tr, 32));
      const float mn = fmaxf(m_, tr);
      const float alpha = __builtin_amdgcn_exp2f(m_ - mn);
      m_ = mn;
      lacc[0] *= alpha; lacc[1] *= alpha; lacc[2] *= alpha; lacc[3] *= alpha;
      #pragma unroll
      for (int df = 0; df < 4; ++df) {
        oacc[df][0] *= alpha; oacc[df][1] *= alpha;
        oacc[df][2] *= alpha; oacc[df][3] *= alpha;
      }
    }
    bf16 p[16];
    #pragma unroll
    for (int i = 0; i < 16; ++i)
      p[i] = (bf16)__builtin_amdgcn_exp2f(v[i] - m_);
    #pragma unroll
    for (int kf = 0; kf < 4; ++kf) {
      bf16x4 pk = {p[kf * 4], p[kf * 4 + 1], p[kf * 4 + 2], p[kf * 4 + 3]};
      *(bf16x4*)pw[kf] = pk;
    }
    bf16x8 pfrag0 = *(const bf16x8*)pr[0];
    bf16x8 pfrag1 = *(const bf16x8*)pr[1];
    const bf16* vt = vs0 + bufi * kdelta;
    __builtin_amdgcn_s_setprio(1);
    #pragma unroll
    for (int df = 0; df < 4; ++df) {
      oacc[df] = mfma16(*(const bf16x8*)(vt + fo[df][0]), pfrag0, oacc[df]);
      oacc[df] = mfma16(*(const bf16x8*)(vt + fo[df][1]), pfrag1, oacc[df]);
    }
    lacc = mfma16(ones, pfrag0, lacc);  // row-sum of P on the matrix pipe
    lacc = mfma16(ones, pfrag1, lacc);
    __builtin_amdgcn_s_setprio(0);
  };

  f32x4 stA[4], stB[4];
  STAGE(0, 0);
  STAGE(1, 1);
  VM("0");
  PH_BAR;
  qkt(stA, 0);  // tile 0 is active for every wave

  const int nit = nkb >> 1;
  for (int i = 0; i < nit; ++i) {
    const int jA = 2 * i, jB = 2 * i + 1;
    // ---- body A: consume tile jA (stA), prefetch QKT(jB)->stB
    if (jA + 2 < nkb) STAGE(jA + 2, (jA + 2) % 3);
    if (jB * 64 <= qw + 15) qkt(stB, jB % 3);
    if (jA * 64 <= qw + 15) smpv(stA, jA, jA % 3);
    VM("0");
    PH_BAR;
    // ---- body B: consume tile jB (stB), prefetch QKT(jB+1)->stA
    if (jB + 2 < nkb) STAGE(jB + 2, (jB + 2) % 3);
    if (jB + 1 < nkb && (jB + 1) * 64 <= qw + 15) qkt(stA, (jB + 1) % 3);
    if (jB * 64 <= qw + 15) smpv(stB, jB, jB % 3);
    VM("0");
    PH_BAR;
  }
#undef STAGE

  const int b = bh >> 4, h = bh & 15;
  const float inv = 1.0f / lacc[0];
  const int s = qw + c;
  #pragma unroll
  for (int df = 0; df < 4; ++df) {
    bf16x4 o;
    #pragma unroll
    for (int rr = 0; rr < 4; ++rr) o[rr] = (bf16)(oacc[df][rr] * inv);
    *(bf16x4*)&O[(size_t)(b * 2048 + s) * ldO + h * 64 + df * 16 + 4 * g] = o;
  }
}

// ---------------- host orchestration ----------------
extern "C" void kernel_launch(void* const* d_in, const int* in_sizes, int n_in,
                              void* d_out, int out_size, void* d_ws, size_t ws_size,
                              hipStream_t stream) {
  const float* x     = (const float*)d_in[0];
  const float* W_qkv = (const float*)d_in[2];
  const float* b_qkv = (const float*)d_in[3];
  const float* W_o   = (const float*)d_in[4];
  const float* b_o   = (const float*)d_in[5];
  const float* ln1w  = (const float*)d_in[6];
  const float* ln1b  = (const float*)d_in[7];
  const float* ln2w  = (const float*)d_in[8];
  const float* ln2b  = (const float*)d_in[9];
  const float* W1    = (const float*)d_in[10];
  const float* b1    = (const float*)d_in[11];
  const float* W2    = (const float*)d_in[12];
  const float* b2    = (const float*)d_in[13];
  const float* freqs = (const float*)d_in[14];
  float* out = (float*)d_out;

  char* ws = (char*)d_ws;
  const size_t MB = (size_t)1 << 20;
  bf16* h1   = (bf16*)(ws + 0 * MB);
  bf16* h2   = (bf16*)(ws + 8 * MB);
  bf16* wQKV = (bf16*)(ws + 16 * MB);
  bf16* wCat = (bf16*)(ws + 22 * MB);
  bf16* w1   = (bf16*)(ws + 32 * MB);
  bf16* qkv  = (bf16*)(ws + 40 * MB);
  bf16* Qb   = (bf16*)(ws + 64 * MB);
  bf16* Kb   = (bf16*)(ws + 72 * MB);
  bf16* VTb  = (bf16*)(ws + 80 * MB);
  bf16* A2   = (bf16*)(ws + 88 * MB);
  float* p0  = (float*)(ws + 0 * MB);
  float* p1  = (float*)(ws + 40 * MB);
  float* p2  = (float*)(ws + 64 * MB);

  ln_dual<<<4096, 256, 0, stream>>>(x, ln1w, ln1b, ln2w, ln2b, h1, h2);
  cast_all<<<9216, 256, 0, stream>>>(W_qkv, W1, W_o, W2, wQKV, w1, wCat);

  gemm256<0><<<192, 512, 0, stream>>>(h1, wQKV, b_qkv, qkv,
                                      nullptr, nullptr, nullptr,
                                      1024, 3072, 192, 12, 16);
  rope_reshape<<<dim3(32, 32), 256, 0, stream>>>(qkv, freqs, Qb, Kb, VTb);
  attn_kernel<<<512, 512, 0, stream>>>(Qb, Kb, VTb, A2, 5120);
  gemm256<1><<<256, 512, 0, stream>>>(h2, w1, b1, A2 + 1024,
                                      nullptr, nullptr, nullptr,
                                      1024, 5120, 256, 16, 16);
  gemm256<2><<<256, 512, 0, stream>>>(A2, wCat, nullptr, p0,
                                      p1, p2, out,
                                      5120, 1024, 64, 4, 20);
  combine_out<<<4096, 256, 0, stream>>>(p0, p1, p2, x, b_o, b2, out);
}

// Round 11
// 196.442 us; speedup vs baseline: 1.3210x; 1.0486x over previous
//
#include <hip/hip_runtime.h>

#define DEV __device__ __forceinline__

typedef __bf16 bf16;
typedef bf16 bf16x4 __attribute__((ext_vector_type(4)));
typedef bf16 bf16x8 __attribute__((ext_vector_type(8)));
typedef float f32x4 __attribute__((ext_vector_type(4)));

DEV f32x4 mfma16(bf16x8 a, bf16x8 b, f32x4 c) {
  return __builtin_amdgcn_mfma_f32_16x16x32_bf16(a, b, c, 0, 0, 0);
}

DEV void gload_lds16(const bf16* g, bf16* l) {
  __builtin_amdgcn_global_load_lds((const __attribute__((address_space(1))) void*)g,
                                   (__attribute__((address_space(3))) void*)l, 16, 0, 0);
}

#define PH_BAR __builtin_amdgcn_s_barrier()
#define VM(NSTR) asm volatile("s_waitcnt vmcnt(" NSTR ")" ::: "memory")
#define WAITBAR(NSTR) asm volatile("s_waitcnt vmcnt(" NSTR ")\n\ts_barrier" ::: "memory")

// tanh-form GELU, exp2+rcp based (~8 VALU ops, overflow-safe both tails).
DEV float fast_gelu(float x) {
  const float z = x * x;
  const float w = __builtin_fmaf(z, 0.1029353f, 2.3019853f);
  const float e = __builtin_amdgcn_exp2f(x * w);
  const float r = __builtin_amdgcn_rcpf(1.0f + e);
  return x - x * r;
}

// ---------------- fused LayerNorm (rows) + all weight casts ----------------
// blocks 0..4095: ln_dual row b
// blocks 4096..7167: W_qkv cast; 7168..11263: W1 cast;
// 11264..12287: W_o row -> wCat[:,0:1024]; 12288..13311: W2 row -> wCat[:,1024:]
__global__ __launch_bounds__(256) void ln_cast_all(
    const float* __restrict__ x,
    const float* __restrict__ ln1w, const float* __restrict__ ln1b,
    const float* __restrict__ ln2w, const float* __restrict__ ln2b,
    bf16* __restrict__ h1, bf16* __restrict__ h2,
    const float* __restrict__ Wqkv_f, const float* __restrict__ W1_f,
    const float* __restrict__ Wo_f, const float* __restrict__ W2_f,
    bf16* __restrict__ wQKV, bf16* __restrict__ w1, bf16* __restrict__ wCat)
{
  const int b = blockIdx.x, t = threadIdx.x;
  if (b < 4096) {
    __shared__ float red[2][4];
    const int lane = t & 63, wave = t >> 6;
    const float4 v = ((const float4*)(x + (size_t)b * 1024))[t];
    float vv[4] = {v.x, v.y, v.z, v.w};
    float s = vv[0] + vv[1] + vv[2] + vv[3];
    float q = vv[0]*vv[0] + vv[1]*vv[1] + vv[2]*vv[2] + vv[3]*vv[3];
    #pragma unroll
    for (int o = 32; o; o >>= 1) { s += __shfl_xor(s, o); q += __shfl_xor(q, o); }
    if (lane == 0) { red[0][wave] = s; red[1][wave] = q; }
    __syncthreads();
    s = red[0][0] + red[0][1] + red[0][2] + red[0][3];
    q = red[1][0] + red[1][1] + red[1][2] + red[1][3];
    const float mu = s * (1.0f / 1024.0f);
    const float var = q * (1.0f / 1024.0f) - mu * mu;
    const float rs = rsqrtf(var + 1e-5f);
    bf16x4 o1, o2;
    #pragma unroll
    for (int j = 0; j < 4; ++j) {
      const int i = t * 4 + j;
      const float xh = (vv[j] - mu) * rs;
      o1[j] = (bf16)(xh * ln1w[i] + ln1b[i]);
      o2[j] = (bf16)(xh * ln2w[i] + ln2b[i]);
    }
    *(bf16x4*)&h1[(size_t)b * 1024 + t * 4] = o1;
    *(bf16x4*)&h2[(size_t)b * 1024 + t * 4] = o2;
    return;
  }
  const int cb = b - 4096;
  if (cb < 3072) {
    const int i = cb * 256 + t;
    const float4 v = ((const float4*)Wqkv_f)[i];
    bf16x4 o = {(bf16)v.x, (bf16)v.y, (bf16)v.z, (bf16)v.w};
    ((bf16x4*)wQKV)[i] = o;
  } else if (cb < 7168) {
    const int i = (cb - 3072) * 256 + t;
    const float4 v = ((const float4*)W1_f)[i];
    bf16x4 o = {(bf16)v.x, (bf16)v.y, (bf16)v.z, (bf16)v.w};
    ((bf16x4*)w1)[i] = o;
  } else if (cb < 8192) {
    const int row = cb - 7168;
    const float4 v = *(const float4*)&Wo_f[(size_t)row * 1024 + t * 4];
    bf16x4 o = {(bf16)v.x, (bf16)v.y, (bf16)v.z, (bf16)v.w};
    *(bf16x4*)&wCat[(size_t)row * 5120 + t * 4] = o;
  } else {
    const int row = cb - 8192;
    #pragma unroll
    for (int k = 0; k < 4; ++k) {
      const int col = t * 4 + k * 1024;
      const float4 v = *(const float4*)&W2_f[(size_t)row * 4096 + col];
      bf16x4 o = {(bf16)v.x, (bf16)v.y, (bf16)v.z, (bf16)v.w};
      *(bf16x4*)&wCat[(size_t)row * 5120 + 1024 + col] = o;
    }
  }
}

// ---------------- GEMM 256x256xBK64, 8 waves, m201-style 4-phase ----------------
DEV bf16x8 ldfrag(const bf16* unit, int lr, int g) {
  return *(const bf16x8*)&unit[lr * 32 + ((g ^ ((lr >> 1) & 3)) << 3)];
}
DEV void read_bfr(const bf16* unit, int blr, int g, bf16x8 bfr[4]) {
  #pragma unroll
  for (int nj = 0; nj < 4; ++nj) bfr[nj] = ldfrag(unit, blr + nj * 16, g);
}
DEV void read_af(const bf16* unit, int alr, int g, bf16x8 af[4]) {
  #pragma unroll
  for (int ml = 0; ml < 4; ++ml) af[ml] = ldfrag(unit, alr + ml * 16, g);
}
DEV void do_mfma(const bf16x8 af[4], const bf16x8 bfr[4], f32x4 acc[8][4], int mh) {
  __builtin_amdgcn_s_setprio(1);
  #pragma unroll
  for (int ml = 0; ml < 4; ++ml)
    #pragma unroll
    for (int nj = 0; nj < 4; ++nj)
      acc[mh * 4 + ml][nj] = mfma16(af[ml], bfr[nj], acc[mh * 4 + ml][nj]);
  __builtin_amdgcn_s_setprio(0);
}

// EPI: 0 = bf16 + bias; 1 = bf16 gelu(acc+bias); 2 = bf16 partial (split-K, no bias)
template <int EPI>
__global__ __launch_bounds__(512) void gemm256(
    const bf16* __restrict__ A, const bf16* __restrict__ B,
    const float* __restrict__ bias, void* __restrict__ Cv,
    void* __restrict__ P1, void* __restrict__ P2, void* __restrict__ P3,
    int K, int ldc, int ntiles, int nbx, int nkt)
{
  __shared__ __align__(16) bf16 As[2][2][2][4096];
  __shared__ __align__(16) bf16 Bs[2][2][2][4096];
  const int tid = threadIdx.x;
  const int lane = tid & 63, wave = tid >> 6;
  const int wm = wave >> 2, wn = wave & 3;
  const int g = lane >> 4, c = lane & 15;
  const int cpx = gridDim.x >> 3;
  const int swz = ((int)blockIdx.x & 7) * cpx + ((int)blockIdx.x >> 3);
  const int tile = swz % ntiles;
  const int sk = swz / ntiles;
  const int bm = (tile / nbx) * 256, bn = (tile % nbx) * 256;

  const int slr = tid >> 2;
  const int sch = (tid & 3) ^ ((tid >> 3) & 3);
  const bf16* aU[2][2];
  const bf16* bU[2][2];
  {
    const bf16* a0 = A + (size_t)(bm + ((slr >> 6) * 128) + (slr & 63)) * K
                       + (size_t)sk * nkt * 64 + sch * 8;
    const bf16* b0 = B + (size_t)(bn + slr) * K + (size_t)sk * nkt * 64 + sch * 8;
    aU[0][0] = a0;            aU[0][1] = a0 + (size_t)64 * K;
    aU[1][0] = a0 + 32;       aU[1][1] = a0 + (size_t)64 * K + 32;
    bU[0][0] = b0;            bU[0][1] = b0 + (size_t)128 * K;
    bU[1][0] = b0 + 32;       bU[1][1] = b0 + (size_t)128 * K + 32;
  }
#define STG_A(bf_, kkh_, ub_, ko_) gload_lds16(aU[kkh_][ub_] + (ko_), &As[bf_][kkh_][ub_][wave * 512])
#define STG_B(bf_, kkh_, ub_, ko_) gload_lds16(bU[kkh_][ub_] + (ko_), &Bs[bf_][kkh_][ub_][wave * 512])

  f32x4 acc[8][4] = {};
  bf16x8 bfr[4], af[4];
  const int alr = (wm << 6) + c;
  const int blr = ((wn & 1) << 6) + c;
  const int bub = wn >> 1;

  STG_B(0, 0, 0, 0); STG_B(0, 0, 1, 0); STG_A(0, 0, 0, 0); STG_A(0, 0, 1, 0);
  STG_B(0, 1, 0, 0); STG_B(0, 1, 1, 0); STG_A(0, 1, 0, 0); STG_A(0, 1, 1, 0);
  WAITBAR("4");

  for (int t = 0; t < nkt - 1; ++t) {
    const int buf = t & 1, nxt = buf ^ 1;
    const int ko = (t + 1) * 64;
    // ---- phase 0: kk=0, mh=0
    read_bfr(&Bs[buf][0][bub][0], blr, g, bfr);
    read_af(&As[buf][0][0][0], alr, g, af);
    STG_B(nxt, 0, 0, ko); STG_B(nxt, 0, 1, ko);
    PH_BAR;
    do_mfma(af, bfr, acc, 0);
    PH_BAR;
    // ---- phase 1: kk=0, mh=1 (bfr reused)
    read_af(&As[buf][0][1][0], alr, g, af);
    STG_A(nxt, 0, 0, ko); STG_A(nxt, 0, 1, ko);
    PH_BAR;
    do_mfma(af, bfr, acc, 1);
    VM("4");
    PH_BAR;
    // ---- phase 2: kk=1, mh=0
    read_bfr(&Bs[buf][1][bub][0], blr, g, bfr);
    read_af(&As[buf][1][0][0], alr, g, af);
    STG_B(nxt, 1, 0, ko); STG_B(nxt, 1, 1, ko);
    PH_BAR;
    do_mfma(af, bfr, acc, 0);
    PH_BAR;
    // ---- phase 3: kk=1, mh=1
    read_af(&As[buf][1][1][0], alr, g, af);
    STG_A(nxt, 1, 0, ko); STG_A(nxt, 1, 1, ko);
    PH_BAR;
    do_mfma(af, bfr, acc, 1);
    VM("4");
    PH_BAR;
  }
  {  // final K-tile: no staging
    const int buf = (nkt - 1) & 1;
    read_bfr(&Bs[buf][0][bub][0], blr, g, bfr);
    read_af(&As[buf][0][0][0], alr, g, af);
    PH_BAR;
    do_mfma(af, bfr, acc, 0);
    PH_BAR;
    read_af(&As[buf][0][1][0], alr, g, af);
    PH_BAR;
    do_mfma(af, bfr, acc, 1);
    VM("0");
    PH_BAR;
    read_bfr(&Bs[buf][1][bub][0], blr, g, bfr);
    read_af(&As[buf][1][0][0], alr, g, af);
    PH_BAR;
    do_mfma(af, bfr, acc, 0);
    PH_BAR;
    read_af(&As[buf][1][1][0], alr, g, af);
    PH_BAR;
    do_mfma(af, bfr, acc, 1);
  }
#undef STG_A
#undef STG_B

  bf16* Pp = nullptr;
  if constexpr (EPI == 2)
    Pp = (bf16*)((sk == 1) ? P1 : (sk == 2) ? P2 : (sk == 3) ? P3 : Cv);
  const int row0 = bm + wm * 128 + 4 * g;
  const int col0 = bn + wn * 64 + c;
  #pragma unroll
  for (int mi = 0; mi < 8; ++mi) {
    #pragma unroll
    for (int nj = 0; nj < 4; ++nj) {
      const int col = col0 + nj * 16;
      float bv = 0.0f;
      if constexpr (EPI < 2) bv = bias[col];
      #pragma unroll
      for (int r = 0; r < 4; ++r) {
        const size_t idx = (size_t)(row0 + mi * 16 + r) * ldc + col;
        float vo = acc[mi][nj][r] + bv;
        if constexpr (EPI == 0) {
          ((bf16*)Cv)[idx] = (bf16)vo;
        } else if constexpr (EPI == 1) {
          ((bf16*)Cv)[idx] = (bf16)fast_gelu(vo);
        } else {
          Pp[idx] = (bf16)vo;
        }
      }
    }
  }
}

// ---------------- combine: out = q0+q1+q2+q3 + x + b_o + b2 ----------------
__global__ __launch_bounds__(256) void combine_out(
    const bf16* __restrict__ q0, const bf16* __restrict__ q1,
    const bf16* __restrict__ q2, const bf16* __restrict__ q3,
    const float* __restrict__ x,
    const float* __restrict__ bo, const float* __restrict__ b2,
    float* __restrict__ out)
{
  const int row = blockIdx.x, t = threadIdx.x;
  const size_t base = (size_t)row * 1024 + t * 4;
  const bf16x4 a0 = *(const bf16x4*)&q0[base];
  const bf16x4 a1 = *(const bf16x4*)&q1[base];
  const bf16x4 a2 = *(const bf16x4*)&q2[base];
  const bf16x4 a3 = *(const bf16x4*)&q3[base];
  const float4 vx = *(const float4*)&x[base];
  const float4 vb = *(const float4*)&bo[t * 4];
  const float4 vc = *(const float4*)&b2[t * 4];
  float4 o;
  o.x = (float)a0[0] + (float)a1[0] + (float)a2[0] + (float)a3[0] + vx.x + vb.x + vc.x;
  o.y = (float)a0[1] + (float)a1[1] + (float)a2[1] + (float)a3[1] + vx.y + vb.y + vc.y;
  o.z = (float)a0[2] + (float)a1[2] + (float)a2[2] + (float)a3[2] + vx.z + vb.z + vc.z;
  o.w = (float)a0[3] + (float)a1[3] + (float)a2[3] + (float)a3[3] + vx.w + vb.w + vc.w;
  *(float4*)&out[base] = o;
}

// ---------------- RoPE + head reshape; also writes V^T ----------------
__global__ __launch_bounds__(256) void rope_reshape(
    const bf16* __restrict__ qkv, const float* __restrict__ freqs,
    bf16* __restrict__ Q, bf16* __restrict__ K, bf16* __restrict__ VT)
{
  __shared__ bf16 vt[64][72];
  const int t = threadIdx.x;
  const int bh = blockIdx.y, b = bh >> 4, h = bh & 15;
  const int sc = blockIdx.x * 64;
  const int sl = t >> 2, s = sc + sl;
  const int d0 = (t & 3) * 16;

  const size_t rowbase = (size_t)(b * 2048 + s) * 3072 + h * 64 + d0;
  const size_t obase = ((size_t)bh * 2048 + s) * 64 + d0;

  #pragma unroll
  for (int which = 0; which < 2; ++which) {
    const bf16* src = qkv + rowbase + which * 1024;
    bf16x8 v0 = *(const bf16x8*)src;
    bf16x8 v1 = *(const bf16x8*)(src + 8);
    if (d0 == 0) {
      bf16x8 r0, r1;
      #pragma unroll
      for (int j = 0; j < 8; ++j) {
        const float cs = freqs[s * 16 + j * 2];
        const float sn = freqs[s * 16 + j * 2 + 1];
        const float x1 = (float)v0[j], x2 = (float)v1[j];
        r0[j] = (bf16)(x1 * cs - x2 * sn);
        r1[j] = (bf16)(x1 * sn + x2 * cs);
      }
      v0 = r0; v1 = r1;
    }
    bf16* dst = (which == 0 ? Q : K) + obase;
    *(bf16x8*)dst = v0;
    *(bf16x8*)(dst + 8) = v1;
  }
  {
    const bf16* src = qkv + rowbase + 2048;
    bf16x8 v0 = *(const bf16x8*)src;
    bf16x8 v1 = *(const bf16x8*)(src + 8);
    #pragma unroll
    for (int j = 0; j < 8; ++j) { vt[sl][d0 + j] = v0[j]; vt[sl][d0 + 8 + j] = v1[j]; }
  }
  __syncthreads();
  {
    const int d = t >> 2;
    const int s0 = (t & 3) * 16;
    bf16x8 o0, o1;
    #pragma unroll
    for (int j = 0; j < 8; ++j) { o0[j] = vt[s0 + j][d]; o1[j] = vt[s0 + 8 + j][d]; }
    bf16* dst = VT + ((size_t)bh * 64 + d) * 2048 + sc + s0;
    *(bf16x8*)dst = o0;
    *(bf16x8*)(dst + 8) = o1;
  }
}

// ---------------- Causal flash attention (v6) ----------------
// R11: 4-buffer K/V (80KB LDS, 2 blocks/CU). Body j: STAGE(j+3) ; qkt(j+1) ;
// smpv(j) ; vmcnt(2) ; barrier. Ledger: end of body j, outstanding =
// {S(j+2), S(j+3)}; VM("2") drains S(j+2) (needed by body j+1's qkt reading
// K[j+2]); S(j+3) stays in flight with ~1.7-body coverage. VM("0") only in
// un-staged tail bodies. Restores counted-vmcnt (T4) that v5 lost, keeping
// qkt-ahead pipeline (T15-lite), mfma row-sum, branch-local max shfls.
__global__ __launch_bounds__(512, 4) void attn_kernel(
    const bf16* __restrict__ Q, const bf16* __restrict__ Kg,
    const bf16* __restrict__ VTg, bf16* __restrict__ O, int ldO)
{
  __shared__ __align__(16) bf16 Ks[4][64][64];
  __shared__ __align__(16) bf16 Vs[4][64][64];
  __shared__ __align__(16) bf16 Ps[8][16][64];

  const int tid = threadIdx.x;
  const int lane = tid & 63, wave = tid >> 6;
  const int g = lane >> 4, c = lane & 15;
  const int L = blockIdx.x;
  const int half = L >> 8, r = L & 255;
  const int bh = (half << 4) | (r >> 4);
  const int qtile = half ? (15 - (r & 15)) : (r & 15);
  const int qw = qtile * 128 + wave * 16;

  const bf16* Qp = Q + (size_t)bh * 2048 * 64;
  const bf16* Kp = Kg + (size_t)bh * 2048 * 64;
  const bf16* Vp = VTg + (size_t)bh * 64 * 2048;

  const int srow = lane >> 3;
  const int schunk = (lane & 7) ^ srow;
  const int svr = wave * 8 + srow;
  const size_t kdelta = (size_t)64 * 64;

  bf16x8 qreg[2];
  {
    const float qs = 0.125f * 1.44269504f;
    bf16x8 t0 = *(const bf16x8*)&Qp[(size_t)(qw + c) * 64 + g * 8];
    bf16x8 t1 = *(const bf16x8*)&Qp[(size_t)(qw + c) * 64 + 32 + g * 8];
    #pragma unroll
    for (int j = 0; j < 8; ++j) {
      qreg[0][j] = (bf16)((float)t0[j] * qs);
      qreg[1][j] = (bf16)((float)t1[j] * qs);
    }
  }
  bf16x8 ones;
  #pragma unroll
  for (int j = 0; j < 8; ++j) ones[j] = (bf16)1.0f;

  const int cq = c & 7;
  int fo[4][2];
  #pragma unroll
  for (int i = 0; i < 4; ++i)
    #pragma unroll
    for (int kk = 0; kk < 2; ++kk)
      fo[i][kk] = (i * 16 + c) * 64 + (((kk * 4 + g) ^ cq) << 3);
  bf16* pw[4];
  #pragma unroll
  for (int kf = 0; kf < 4; ++kf)
    pw[kf] = &Ps[wave][c][((((kf * 2 + (g >> 1)) ^ cq) << 3)) + ((g & 1) << 2)];
  const bf16* pr[2];
  #pragma unroll
  for (int kk = 0; kk < 2; ++kk)
    pr[kk] = &Ps[wave][c][((kk * 4 + g) ^ cq) << 3];
  const bf16* ks0 = &Ks[0][0][0];
  const bf16* vs0 = &Vs[0][0][0];

  f32x4 oacc[4] = {};
  f32x4 lacc = {};
  float m_ = -1e30f;

  const int nkb = 2 * qtile + 2;  // even, >= 2
#define STAGE(j_) do { const int b4_ = (j_) & 3;                                   \
    gload_lds16(&Kp[(size_t)((j_) * 64 + svr) * 64 + schunk * 8], &Ks[b4_][wave * 8][0]); \
    gload_lds16(&Vp[(size_t)svr * 2048 + (j_) * 64 + schunk * 8], &Vs[b4_][wave * 8][0]); \
  } while (0)

  auto qkt = [&](f32x4* st, int bufi) {
    const bf16* kt = ks0 + bufi * kdelta;
    __builtin_amdgcn_s_setprio(1);
    #pragma unroll
    for (int kf = 0; kf < 4; ++kf) {
      f32x4 z = {};
      z = mfma16(*(const bf16x8*)(kt + fo[kf][0]), qreg[0], z);
      st[kf] = mfma16(*(const bf16x8*)(kt + fo[kf][1]), qreg[1], z);
    }
    __builtin_amdgcn_s_setprio(0);
  };

  auto smpv = [&](const f32x4* st, int j_, int bufi) {
    const int kbase = j_ * 64;
    float v[16];
    if (kbase + 63 > qw) {
      const int qrel = qw + c - kbase;
      #pragma unroll
      for (int kf = 0; kf < 4; ++kf)
        #pragma unroll
        for (int rr = 0; rr < 4; ++rr)
          v[kf * 4 + rr] = (kf * 16 + 4 * g + rr <= qrel) ? st[kf][rr] : -1e30f;
    } else {
      #pragma unroll
      for (int kf = 0; kf < 4; ++kf)
        #pragma unroll
        for (int rr = 0; rr < 4; ++rr)
          v[kf * 4 + rr] = st[kf][rr];
    }
    float u0 = fmaxf(fmaxf(v[0], v[1]), v[2]);
    float u1 = fmaxf(fmaxf(v[3], v[4]), v[5]);
    float u2 = fmaxf(fmaxf(v[6], v[7]), v[8]);
    float u3 = fmaxf(fmaxf(v[9], v[10]), v[11]);
    float u4 = fmaxf(fmaxf(v[12], v[13]), v[14]);
    float tm = fmaxf(fmaxf(fmaxf(u0, u1), u2), fmaxf(fmaxf(u3, u4), v[15]));
    if (__any(tm > m_ + 8.0f)) {
      float tr = fmaxf(tm, __shfl_xor(tm, 16));
      tr = fmaxf(tr, __shfl_xor(tr, 32));
      const float mn = fmaxf(m_, tr);
      const float alpha = __builtin_amdgcn_exp2f(m_ - mn);
      m_ = mn;
      lacc[0] *= alpha; lacc[1] *= alpha; lacc[2] *= alpha; lacc[3] *= alpha;
      #pragma unroll
      for (int df = 0; df < 4; ++df) {
        oacc[df][0] *= alpha; oacc[df][1] *= alpha;
        oacc[df][2] *= alpha; oacc[df][3] *= alpha;
      }
    }
    bf16 p[16];
    #pragma unroll
    for (int i = 0; i < 16; ++i)
      p[i] = (bf16)__builtin_amdgcn_exp2f(v[i] - m_);
    #pragma unroll
    for (int kf = 0; kf < 4; ++kf) {
      bf16x4 pk = {p[kf * 4], p[kf * 4 + 1], p[kf * 4 + 2], p[kf * 4 + 3]};
      *(bf16x4*)pw[kf] = pk;
    }
    bf16x8 pfrag0 = *(const bf16x8*)pr[0];
    bf16x8 pfrag1 = *(const bf16x8*)pr[1];
    const bf16* vt = vs0 + bufi * kdelta;
    __builtin_amdgcn_s_setprio(1);
    #pragma unroll
    for (int df = 0; df < 4; ++df) {
      oacc[df] = mfma16(*(const bf16x8*)(vt + fo[df][0]), pfrag0, oacc[df]);
      oacc[df] = mfma16(*(const bf16x8*)(vt + fo[df][1]), pfrag1, oacc[df]);
    }
    lacc = mfma16(ones, pfrag0, lacc);
    lacc = mfma16(ones, pfrag1, lacc);
    __builtin_amdgcn_s_setprio(0);
  };

  f32x4 stA[4], stB[4];
  STAGE(0); STAGE(1); STAGE(2);
  VM("2");   // S0,S1 drained; S2 in flight
  PH_BAR;
  qkt(stA, 0);

  const int nit = nkb >> 1;
  for (int i = 0; i < nit; ++i) {
    const int jA = 2 * i, jB = 2 * i + 1;
    // ---- body A: consume tile jA (stA), prefetch QKT(jB)->stB, stage jA+3
    const bool stgA = (jA + 3 < nkb);
    if (stgA) STAGE(jA + 3);
    if (jB * 64 <= qw + 15) qkt(stB, jB & 3);
    smpv(stA, jA, jA & 3);
    if (stgA) { VM("2"); } else { VM("0"); }
    PH_BAR;
    // ---- body B: consume tile jB (stB), prefetch QKT(jB+1)->stA, stage jB+3
    const bool stgB = (jB + 3 < nkb);
    if (stgB) STAGE(jB + 3);
    if (jB + 1 < nkb && (jB + 1) * 64 <= qw + 15) qkt(stA, (jB + 1) & 3);
    if (jB * 64 <= qw + 15) smpv(stB, jB, jB & 3);
    if (stgB) { VM("2"); } else { VM("0"); }
    PH_BAR;
  }
#undef STAGE

  const int b = bh >> 4, h = bh & 15;
  const float inv = 1.0f / lacc[0];
  const int s = qw + c;
  #pragma unroll
  for (int df = 0; df < 4; ++df) {
    bf16x4 o;
    #pragma unroll
    for (int rr = 0; rr < 4; ++rr) o[rr] = (bf16)(oacc[df][rr] * inv);
    *(bf16x4*)&O[(size_t)(b * 2048 + s) * ldO + h * 64 + df * 16 + 4 * g] = o;
  }
}

// ---------------- host orchestration ----------------
extern "C" void kernel_launch(void* const* d_in, const int* in_sizes, int n_in,
                              void* d_out, int out_size, void* d_ws, size_t ws_size,
                              hipStream_t stream) {
  const float* x     = (const float*)d_in[0];
  const float* W_qkv = (const float*)d_in[2];
  const float* b_qkv = (const float*)d_in[3];
  const float* W_o   = (const float*)d_in[4];
  const float* b_o   = (const float*)d_in[5];
  const float* ln1w  = (const float*)d_in[6];
  const float* ln1b  = (const float*)d_in[7];
  const float* ln2w  = (const float*)d_in[8];
  const float* ln2b  = (const float*)d_in[9];
  const float* W1    = (const float*)d_in[10];
  const float* b1    = (const float*)d_in[11];
  const float* W2    = (const float*)d_in[12];
  const float* b2    = (const float*)d_in[13];
  const float* freqs = (const float*)d_in[14];
  float* out = (float*)d_out;

  char* ws = (char*)d_ws;
  const size_t MB = (size_t)1 << 20;
  // live ranges (MB): h1 0-8 (dead after QKV), h2 8-16 (dead after FF1),
  // wQKV 16-22, wCat 22-32, w1 32-40, qkv 40-64 (dead after rope),
  // Qb 64-72, Kb 72-80, VTb 80-88 (dead after attn), A2 88-128.
  // bf16 split-K partials reuse dead regions: q0@0, q1@8, q2@40, q3@48.
  bf16* h1   = (bf16*)(ws + 0 * MB);
  bf16* h2   = (bf16*)(ws + 8 * MB);
  bf16* wQKV = (bf16*)(ws + 16 * MB);
  bf16* wCat = (bf16*)(ws + 22 * MB);
  bf16* w1   = (bf16*)(ws + 32 * MB);
  bf16* qkv  = (bf16*)(ws + 40 * MB);
  bf16* Qb   = (bf16*)(ws + 64 * MB);
  bf16* Kb   = (bf16*)(ws + 72 * MB);
  bf16* VTb  = (bf16*)(ws + 80 * MB);
  bf16* A2   = (bf16*)(ws + 88 * MB);
  bf16* q0   = (bf16*)(ws + 0 * MB);
  bf16* q1   = (bf16*)(ws + 8 * MB);
  bf16* q2   = (bf16*)(ws + 40 * MB);
  bf16* q3   = (bf16*)(ws + 48 * MB);

  ln_cast_all<<<13312, 256, 0, stream>>>(x, ln1w, ln1b, ln2w, ln2b, h1, h2,
                                         W_qkv, W1, W_o, W2, wQKV, w1, wCat);

  gemm256<0><<<192, 512, 0, stream>>>(h1, wQKV, b_qkv, qkv,
                                      nullptr, nullptr, nullptr,
                                      1024, 3072, 192, 12, 16);
  rope_reshape<<<dim3(32, 32), 256, 0, stream>>>(qkv, freqs, Qb, Kb, VTb);
  attn_kernel<<<512, 512, 0, stream>>>(Qb, Kb, VTb, A2, 5120);
  gemm256<1><<<256, 512, 0, stream>>>(h2, w1, b1, A2 + 1024,
                                      nullptr, nullptr, nullptr,
                                      1024, 5120, 256, 16, 16);
  gemm256<2><<<256, 512, 0, stream>>>(A2, wCat, nullptr, q0,
                                      q1, q2, q3,
                                      5120, 1024, 64, 4, 20);
  combine_out<<<4096, 256, 0, stream>>>(q0, q1, q2, q3, x, b_o, b2, out);
}